// Round 11
// baseline (669.444 us; speedup 1.0000x reference)
//
#include <hip/hip_runtime.h>
#include <hip/hip_bf16.h>
#include <hip/hip_cooperative_groups.h>

namespace cg = cooperative_groups;

namespace {
constexpr int kHW   = 40;
constexpr int kNPIX = kHW * kHW;        // 1600
constexpr int kDIM  = 256;
constexpr int kPADW = 42;
constexpr int kACOL = 648;              // heads * 9 * 9
constexpr float kSCALE = 0.17677669529663687f;  // 32^-0.5
constexpr int kGRID = 512;              // 2 blocks/CU — co-resident guaranteed
}

using bf16 = __hip_bfloat16;
typedef __attribute__((ext_vector_type(8))) short sh8;    // 8 bf16 (A/B frag)
typedef __attribute__((ext_vector_type(4))) float f32x4;  // C/D frag

static __device__ __forceinline__ bf16 f2bf(float f)  { return __float2bfloat16(f); }
static __device__ __forceinline__ float bf2f(bf16 b)  { return __bfloat162float(b); }
static __device__ __forceinline__ float sraw2f(short s) {
  union { unsigned int u; float f; } c;
  c.u = ((unsigned int)(unsigned short)s) << 16;
  return c.f;
}

struct KParams {
  const float *x, *fg, *bg;
  const float *Wc1, *s1, *b1, *Wc2, *s2, *b2;
  const float *Wv, *bv, *Wfg, *bfg, *Wbg, *bbg, *Wp, *bp;
  const float *Wc3, *s3, *b3, *Wc4, *s4, *b4;
  float* out;
  bf16 *LgF, *LgB, *XWb, *SHf, *SHb, *Vb, *X1b;
  bf16 *Wt1, *Wt2, *Wt3, *Wt4, *WaTf, *WaTb, *WvT, *WpT, *Pb0, *Pb1;
};

// ---------------------------------------------------------------------------
// prep virtual-block body (identical segmentation to the verified prep_all).
__device__ __forceinline__ void prep_body(const KParams& p, int b, int t,
                                          char* smemRaw) {
  float* smem = (float*)smemRaw;                 // 2304 floats
  float (*tile)[33] = (float(*)[33])smemRaw;     // 32x33 view

  if (b < 1024) {                       // conv weight transform
    int w = b >> 8, oc = b & 255;
    const float* src = (w == 0) ? p.Wc1 : (w == 1) ? p.Wc2 : (w == 2) ? p.Wc3 : p.Wc4;
    bf16* dst        = (w == 0) ? p.Wt1 : (w == 1) ? p.Wt2 : (w == 2) ? p.Wt3 : p.Wt4;
    src += (size_t)oc * 2304;
    for (int i = t; i < 2304; i += 256) smem[i] = src[i];
    __syncthreads();
#pragma unroll
    for (int tap = 0; tap < 9; ++tap)
      dst[(size_t)(tap * 256 + oc) * 256 + t] = f2bf(smem[t * 9 + tap]);
    return;
  }

  int tx = t & 31, ty = t >> 5;

  if (b < 1360) {                       // Wa transposes (256x648 -> 672x256)
    int b2 = b - 1024;
    const float* in = (b2 < 168) ? p.Wfg : p.Wbg;
    bf16* outp      = (b2 < 168) ? p.WaTf : p.WaTb;
    int rb = b2 % 168;
    int bx = rb % 21, by = rb / 21;
    int c0 = bx * 32, r0 = by * 32;
#pragma unroll
    for (int rr = ty; rr < 32; rr += 8) {
      int c = c0 + tx;
      tile[rr][tx] = (c < kACOL) ? in[(size_t)(r0 + rr) * kACOL + c] : 0.f;
    }
    __syncthreads();
#pragma unroll
    for (int rr = ty; rr < 32; rr += 8)
      outp[(size_t)(c0 + rr) * 256 + r0 + tx] = f2bf(tile[tx][rr]);
    return;
  }

  if (b < 1488) {                       // Wv / Wp transpose (256x256)
    int b3 = b - 1360;
    const float* in = (b3 < 64) ? p.Wv : p.Wp;
    bf16* outp      = (b3 < 64) ? p.WvT : p.WpT;
    int rb = b3 & 63;
    int bx = rb & 7, by = rb >> 3;
    int c0 = bx * 32, r0 = by * 32;
#pragma unroll
    for (int rr = ty; rr < 32; rr += 8)
      tile[rr][tx] = in[(size_t)(r0 + rr) * 256 + c0 + tx];
    __syncthreads();
#pragma unroll
    for (int rr = ty; rr < 32; rr += 8)
      outp[(size_t)(c0 + rr) * 256 + r0 + tx] = f2bf(tile[tx][rr]);
    return;
  }

  if (b < 2288) {                       // fg/bg CHW -> HWC bf16
    int b4 = b - 1488;
    const float* in = (b4 < 400) ? p.fg : p.bg;
    bf16* outp      = (b4 < 400) ? p.SHf : p.SHb;
    int rb = b4 % 400;
    int bx = rb % 50, by = rb / 50;
    int c0 = bx * 32, r0 = by * 32;
#pragma unroll
    for (int rr = ty; rr < 32; rr += 8)
      tile[rr][tx] = in[(size_t)(r0 + rr) * kNPIX + c0 + tx];
    __syncthreads();
#pragma unroll
    for (int rr = ty; rr < 32; rr += 8)
      outp[(size_t)(c0 + rr) * 256 + r0 + tx] = f2bf(tile[tx][rr]);
    return;
  }

  if (b < 2688) {                       // x CHW -> padded HWC bf16 interior
    int b5 = b - 2288;
    int bx = b5 % 50, by = b5 / 50;
    int c0 = bx * 32, r0 = by * 32;
#pragma unroll
    for (int rr = ty; rr < 32; rr += 8)
      tile[rr][tx] = p.x[(size_t)(r0 + rr) * kNPIX + c0 + tx];
    __syncthreads();
#pragma unroll
    for (int rr = ty; rr < 32; rr += 8) {
      int l = c0 + rr;
      int yy = l / kHW, xx = l % kHW;
      p.Pb0[(size_t)((yy + 1) * kPADW + xx + 1) * kDIM + r0 + tx] = f2bf(tile[tx][rr]);
    }
    return;
  }

  {                                     // zero pad borders of Pb0 & Pb1
    int k = b - 2688;                   // 0..163
    int py, px;
    if (k < 42)      { py = 0;          px = k; }
    else if (k < 84) { py = 41;         px = k - 42; }
    else if (k < 124){ py = k - 84 + 1; px = 0; }
    else             { py = k - 124 + 1; px = 41; }
    size_t off = (size_t)(py * kPADW + px) * kDIM + t;
    p.Pb0[off] = f2bf(0.f);
    p.Pb1[off] = f2bf(0.f);
  }
}

// ---------------------------------------------------------------------------
// Verified R8 conv body: 32 pix x 32 oc, 4-wave K-split, LDS reduce.
__device__ __forceinline__ void conv_body(const bf16* __restrict__ act,
                                          const bf16* __restrict__ wt,
                                          const float* __restrict__ sc,
                                          const float* __restrict__ sh_,
                                          bf16* __restrict__ outPad,
                                          float* __restrict__ outF32,
                                          int vb, int tid, char* smemRaw) {
  int pt  = vb % 50;
  int oc0 = (vb / 50) * 32;
  int ty0 = (pt / 5) * 4;
  int tx0 = (pt % 5) * 8;
  int w = tid >> 6, lane = tid & 63, g = lane >> 4, r16 = lane & 15;

  int dy0 = r16 >> 3,       dx0 = r16 & 7;
  int dy1 = 2 + (r16 >> 3), dx1 = r16 & 7;

  f32x4 acc[2][2] = {};
  int icq = w * 64;

#pragma unroll
  for (int t = 0; t < 9; ++t) {
    int tyy = t / 3, txx = t % 3;
    const bf16* aBase0 = act + (size_t)((ty0 + dy0 + tyy) * kPADW + tx0 + dx0 + txx) * kDIM;
    const bf16* aBase1 = act + (size_t)((ty0 + dy1 + tyy) * kPADW + tx0 + dx1 + txx) * kDIM;
    const bf16* bBase  = wt + (size_t)(t * 256 + oc0 + r16) * 256;
#pragma unroll
    for (int kk = 0; kk < 2; ++kk) {
      int ic = icq + kk * 32 + g * 8;
      sh8 a0 = *(const sh8*)(aBase0 + ic);
      sh8 a1 = *(const sh8*)(aBase1 + ic);
      sh8 b0 = *(const sh8*)(bBase + ic);
      sh8 b1 = *(const sh8*)(bBase + 16 * 256 + ic);
      acc[0][0] = __builtin_amdgcn_mfma_f32_16x16x32_bf16(a0, b0, acc[0][0], 0, 0, 0);
      acc[0][1] = __builtin_amdgcn_mfma_f32_16x16x32_bf16(a0, b1, acc[0][1], 0, 0, 0);
      acc[1][0] = __builtin_amdgcn_mfma_f32_16x16x32_bf16(a1, b0, acc[1][0], 0, 0, 0);
      acc[1][1] = __builtin_amdgcn_mfma_f32_16x16x32_bf16(a1, b1, acc[1][1], 0, 0, 0);
    }
  }

  typedef float Red[32][33];
  Red* red = (Red*)smemRaw;             // [4][32][33]
#pragma unroll
  for (int mi = 0; mi < 2; ++mi)
#pragma unroll
    for (int ni = 0; ni < 2; ++ni)
#pragma unroll
      for (int q = 0; q < 4; ++q)
        red[w][mi * 16 + g * 4 + q][ni * 16 + r16] = acc[mi][ni][q];
  __syncthreads();

  int pixL = tid >> 3;
  int ocL  = (tid & 7) * 4;
  int dy = pixL >> 3, dx = pixL & 7;
  int oc = oc0 + ocL;
  int y = ty0 + dy, x = tx0 + dx;
  float v[4];
#pragma unroll
  for (int j = 0; j < 4; ++j) {
    float s = red[0][pixL][ocL + j] + red[1][pixL][ocL + j] +
              red[2][pixL][ocL + j] + red[3][pixL][ocL + j];
    v[j] = fmaxf(fmaf(s, sc[oc + j], sh_[oc + j]), 0.f);
  }
  if (outPad) {
    bf16 pk[4];
#pragma unroll
    for (int j = 0; j < 4; ++j) pk[j] = f2bf(v[j]);
    *reinterpret_cast<uint2*>(outPad + (size_t)((y + 1) * kPADW + x + 1) * kDIM + oc) =
        *reinterpret_cast<uint2*>(pk);
  } else {
#pragma unroll
    for (int j = 0; j < 4; ++j)
      outF32[(oc + j) * kNPIX + y * kHW + x] = v[j];
  }
}

// ---------------------------------------------------------------------------
// Verified gemm3 virtual-block body.
__device__ __forceinline__ void gemm3_body(const KParams& p, int b, int tid,
                                           char* smemRaw) {
  const bf16 *A, *Bt;
  const float* bias;
  bf16 *oV = nullptr, *oLg = nullptr;
  bool padded = false;
  int l0, col0;
  if (b < 400) {
    padded = true; A = p.Pb0; Bt = p.WvT; bias = p.bv; oV = p.Vb;
    l0 = (b % 50) * 32; col0 = (b / 50) * 32;
  } else if (b < 1450) {
    int b2 = b - 400;
    A = p.SHf; Bt = p.WaTf; bias = p.bfg; oLg = p.LgF;
    l0 = (b2 % 50) * 32; col0 = (b2 / 50) * 32;
  } else {
    int b2 = b - 1450;
    A = p.SHb; Bt = p.WaTb; bias = p.bbg; oLg = p.LgB;
    l0 = (b2 % 50) * 32; col0 = (b2 / 50) * 32;
  }

  int w = tid >> 6, lane = tid & 63, g = lane >> 4, r16 = lane & 15;

  const bf16* aBase[2];
#pragma unroll
  for (int mi = 0; mi < 2; ++mi) {
    int l = l0 + mi * 16 + r16;
    if (padded) {
      int y = l / kHW, x = l % kHW;
      aBase[mi] = A + (size_t)((y + 1) * kPADW + x + 1) * kDIM;
    } else {
      aBase[mi] = A + (size_t)l * kDIM;
    }
  }
  const bf16* bBase0 = Bt + (size_t)(col0 + r16) * kDIM;
  const bf16* bBase1 = bBase0 + 16 * kDIM;

  f32x4 acc[2][2] = {};
  int icq = w * 64 + g * 8;
#pragma unroll
  for (int kk = 0; kk < 2; ++kk) {
    int ic = icq + kk * 32;
    sh8 a0 = *(const sh8*)(aBase[0] + ic);
    sh8 a1 = *(const sh8*)(aBase[1] + ic);
    sh8 b0 = *(const sh8*)(bBase0 + ic);
    sh8 b1 = *(const sh8*)(bBase1 + ic);
    acc[0][0] = __builtin_amdgcn_mfma_f32_16x16x32_bf16(a0, b0, acc[0][0], 0, 0, 0);
    acc[0][1] = __builtin_amdgcn_mfma_f32_16x16x32_bf16(a0, b1, acc[0][1], 0, 0, 0);
    acc[1][0] = __builtin_amdgcn_mfma_f32_16x16x32_bf16(a1, b0, acc[1][0], 0, 0, 0);
    acc[1][1] = __builtin_amdgcn_mfma_f32_16x16x32_bf16(a1, b1, acc[1][1], 0, 0, 0);
  }

  typedef float Red[32][33];
  Red* red = (Red*)smemRaw;
#pragma unroll
  for (int mi = 0; mi < 2; ++mi)
#pragma unroll
    for (int ni = 0; ni < 2; ++ni)
#pragma unroll
      for (int q = 0; q < 4; ++q)
        red[w][mi * 16 + g * 4 + q][ni * 16 + r16] = acc[mi][ni][q];
  __syncthreads();

  int pixL = tid >> 3;
  int ocL  = (tid & 7) * 4;
  int l = l0 + pixL;
  int col = col0 + ocL;

  float s[4];
#pragma unroll
  for (int j = 0; j < 4; ++j)
    s[j] = red[0][pixL][ocL + j] + red[1][pixL][ocL + j] +
           red[2][pixL][ocL + j] + red[3][pixL][ocL + j];

  if (oLg) {
#pragma unroll
    for (int j = 0; j < 4; ++j)
      if (col + j < kACOL)
        oLg[(size_t)l * kACOL + col + j] = f2bf((s[j] + bias[col + j]) * kSCALE);
  } else {
    bf16 pk[4];
#pragma unroll
    for (int j = 0; j < 4; ++j) pk[j] = f2bf(s[j] + bias[col + j]);
    *reinterpret_cast<uint2*>(oV + (size_t)l * kDIM + col) =
        *reinterpret_cast<uint2*>(pk);
  }
}

// ---------------------------------------------------------------------------
// Verified softmax_pv virtual-block body (vb = pixel).
__device__ __forceinline__ void smpv_body(const bf16* __restrict__ Lg,
                                          const bf16* __restrict__ v_hwc,
                                          bf16* __restrict__ xw,
                                          int l, int t, char* smemRaw) {
  float* att = (float*)smemRaw;                   // 648
  float (*vu)[kDIM] = (float(*)[kDIM])(att + 648);// 9 x 256

  int y = l / kHW, x = l % kHW;

#pragma unroll
  for (int r = 0; r < 3; ++r) {
    int a = t + r * 256;
    if (a < kACOL) att[a] = bf2f(Lg[(size_t)l * kACOL + a]);
  }
#pragma unroll
  for (int q = 0; q < 9; ++q) {
    int qy = y + q / 3 - 1;
    int qx = x + q % 3 - 1;
    bool ok = (qy >= 0 && qy < kHW && qx >= 0 && qx < kHW);
    vu[q][t] = ok ? bf2f(v_hwc[(size_t)(qy * kHW + qx) * kDIM + t]) : 0.f;
  }
  __syncthreads();

  if (t < 72) {
    float* gp = &att[t * 9];
    float m = gp[0];
#pragma unroll
    for (int q = 1; q < 9; ++q) m = fmaxf(m, gp[q]);
    float e[9], sm = 0.f;
#pragma unroll
    for (int q = 0; q < 9; ++q) { e[q] = __expf(gp[q] - m); sm += e[q]; }
    float inv = 1.f / sm;
#pragma unroll
    for (int q = 0; q < 9; ++q) gp[q] = e[q] * inv;
  }
  __syncthreads();

  int n = t >> 5;
  const float* an = &att[n * 81];
#pragma unroll
  for (int pp = 0; pp < 9; ++pp) {
    float acc = 0.f;
#pragma unroll
    for (int q = 0; q < 9; ++q)
      acc = fmaf(an[pp * 9 + q], vu[q][t], acc);
    xw[(size_t)(l * 9 + pp) * kDIM + t] = f2bf(acc);
  }
}

// ---------------------------------------------------------------------------
// foldproj adapted to 256 threads: fold 512 tasks (2/thread), then 4 waves x
// 2 col-tiles full-K GEMM from LDS. mode 1: flat HWC; mode 2: padded HWC.
__device__ __forceinline__ void foldproj_body(const bf16* __restrict__ xw,
                                              const bf16* __restrict__ Bt,
                                              const float* __restrict__ bias,
                                              bf16* __restrict__ oBf,
                                              int mode, int vb, int tid,
                                              char* smemRaw) {
  bf16 (*fold_s)[264] = (bf16(*)[264])smemRaw;   // 16 x 264 bf16 = 8448 B
  int l0 = vb * 16;

  for (int task = tid; task < 512; task += 256) {
    int s  = task >> 5;
    int cb = (task & 31) * 8;
    int l = l0 + s;
    int Y = l / kHW, X = l % kHW;
    float facc[8] = {};
#pragma unroll
    for (int i = 0; i < 3; ++i) {
      int ys = Y + 1 - i;
      if (ys < 0 || ys >= kHW) continue;
#pragma unroll
      for (int j = 0; j < 3; ++j) {
        int xs = X + 1 - j;
        if (xs < 0 || xs >= kHW) continue;
        sh8 v = *(const sh8*)(xw + (size_t)((ys * kHW + xs) * 9 + i * 3 + j) * kDIM + cb);
#pragma unroll
        for (int e = 0; e < 8; ++e) facc[e] += sraw2f(v[e]);
      }
    }
    bf16 pk[8];
#pragma unroll
    for (int e = 0; e < 8; ++e) pk[e] = f2bf(facc[e]);
    *reinterpret_cast<sh8*>(&fold_s[s][cb]) = *reinterpret_cast<sh8*>(pk);
  }
  __syncthreads();

  int w = tid >> 6, lane = tid & 63, g = lane >> 4, r16 = lane & 15;
#pragma unroll
  for (int ct = 0; ct < 2; ++ct) {
    int col0 = (w + ct * 4) * 32;
    const bf16* bBase0 = Bt + (size_t)(col0 + r16) * kDIM;
    const bf16* bBase1 = bBase0 + 16 * kDIM;

    f32x4 acc[2] = {};
#pragma unroll
    for (int kk = 0; kk < 8; ++kk) {
      int k = kk * 32 + g * 8;
      sh8 a  = *(const sh8*)(&fold_s[r16][k]);
      sh8 b0 = *(const sh8*)(bBase0 + k);
      sh8 b1 = *(const sh8*)(bBase1 + k);
      acc[0] = __builtin_amdgcn_mfma_f32_16x16x32_bf16(a, b0, acc[0], 0, 0, 0);
      acc[1] = __builtin_amdgcn_mfma_f32_16x16x32_bf16(a, b1, acc[1], 0, 0, 0);
    }

#pragma unroll
    for (int ni = 0; ni < 2; ++ni) {
      int col = col0 + ni * 16 + r16;
      float bb = bias[col];
#pragma unroll
      for (int q = 0; q < 4; ++q) {
        int l = l0 + g * 4 + q;
        bf16 val = f2bf(acc[ni][q] + bb);
        if (mode == 1) {
          oBf[(size_t)l * kDIM + col] = val;
        } else {
          int y = l / kHW, xx = l % kHW;
          oBf[(size_t)((y + 1) * kPADW + xx + 1) * kDIM + col] = val;
        }
      }
    }
  }
}

// ---------------------------------------------------------------------------
// THE cooperative mega-kernel: 10 phases, 9 grid syncs.
__global__ __launch_bounds__(256) void fused_all(KParams p) {
  cg::grid_group grid = cg::this_grid();
  __shared__ __align__(16) char smemRaw[4 * 32 * 33 * 4];  // 16896 B union
  int b = blockIdx.x, t = threadIdx.x;

  // P0: prep (2852 vb)
  for (int vb = b; vb < 2852; vb += kGRID) {
    prep_body(p, vb, t, smemRaw);
    __syncthreads();
  }
  grid.sync();

  // P1: conv1  Pb0 -> Pb1
  if (b < 400) conv_body(p.Pb0, p.Wt1, p.s1, p.b1, p.Pb1, nullptr, b, t, smemRaw);
  grid.sync();

  // P2: conv2  Pb1 -> Pb0 (h0)
  if (b < 400) conv_body(p.Pb1, p.Wt2, p.s2, p.b2, p.Pb0, nullptr, b, t, smemRaw);
  grid.sync();

  // P3: gemm3 (2500 vb): v, logitsF, logitsB
  for (int vb = b; vb < 2500; vb += kGRID) {
    gemm3_body(p, vb, t, smemRaw);
    __syncthreads();
  }
  grid.sync();

  // P4: softmax+PV fg (1600 vb)
  for (int vb = b; vb < kNPIX; vb += kGRID) {
    smpv_body(p.LgF, p.Vb, p.XWb, vb, t, smemRaw);
    __syncthreads();
  }
  grid.sync();

  // P5: fold+proj fg -> X1b (flat)
  if (b < 100) foldproj_body(p.XWb, p.WpT, p.bp, p.X1b, 1, b, t, smemRaw);
  grid.sync();

  // P6: softmax+PV bg (v = x1)
  for (int vb = b; vb < kNPIX; vb += kGRID) {
    smpv_body(p.LgB, p.X1b, p.XWb, vb, t, smemRaw);
    __syncthreads();
  }
  grid.sync();

  // P7: fold+proj bg -> Pb1 (padded)
  if (b < 100) foldproj_body(p.XWb, p.WpT, p.bp, p.Pb1, 2, b, t, smemRaw);
  grid.sync();

  // P8: conv3  Pb1 -> Pb0
  if (b < 400) conv_body(p.Pb1, p.Wt3, p.s3, p.b3, p.Pb0, nullptr, b, t, smemRaw);
  grid.sync();

  // P9: conv4  Pb0 -> out (f32 NCHW)
  if (b < 400) conv_body(p.Pb0, p.Wt4, p.s4, p.b4, nullptr, p.out, b, t, smemRaw);
}

// ---------------------------------------------------------------------------
extern "C" void kernel_launch(void* const* d_in, const int* in_sizes, int n_in,
                              void* d_out, int out_size, void* d_ws, size_t ws_size,
                              hipStream_t stream) {
  float* ws = (float*)d_ws;
  KParams p;
  p.x   = (const float*)d_in[0];
  p.fg  = (const float*)d_in[1];
  p.bg  = (const float*)d_in[2];
  p.Wc1 = (const float*)d_in[3];
  p.s1  = (const float*)d_in[4];
  p.b1  = (const float*)d_in[5];
  p.Wc2 = (const float*)d_in[6];
  p.s2  = (const float*)d_in[7];
  p.b2  = (const float*)d_in[8];
  p.Wv  = (const float*)d_in[9];
  p.bv  = (const float*)d_in[10];
  p.Wfg = (const float*)d_in[11];
  p.bfg = (const float*)d_in[12];
  p.Wbg = (const float*)d_in[13];
  p.bbg = (const float*)d_in[14];
  p.Wp  = (const float*)d_in[15];
  p.bp  = (const float*)d_in[16];
  p.Wc3 = (const float*)d_in[17];
  p.s3  = (const float*)d_in[18];
  p.b3  = (const float*)d_in[19];
  p.Wc4 = (const float*)d_in[20];
  p.s4  = (const float*)d_in[21];
  p.b4  = (const float*)d_in[22];
  p.out = (float*)d_out;

  p.LgF  = (bf16*)ws;                   // 1600x648 bf16  (518400 w)
  p.LgB  = (bf16*)(ws + 518400);
  p.XWb  = (bf16*)(ws + 1036800);       // 3686400 bf16
  p.SHf  = (bf16*)(ws + 2880000);
  p.SHb  = (bf16*)(ws + 3084800);
  p.Vb   = (bf16*)(ws + 3494400);
  p.X1b  = (bf16*)(ws + 3699200);
  p.Wt1  = (bf16*)(ws + 3904000);
  p.Wt2  = p.Wt1 + 589824;
  p.Wt3  = p.Wt2 + 589824;
  p.Wt4  = p.Wt3 + 589824;
  p.WaTf = (bf16*)(ws + 5083648);
  p.WaTb = (bf16*)(ws + 5169664);
  p.WvT  = (bf16*)(ws + 5255680);
  p.WpT  = (bf16*)(ws + 5288448);
  p.Pb0  = (bf16*)(ws + 5321216);
  p.Pb1  = (bf16*)(ws + 5547008);
  // end: 5772800 words = 23.09 MB

  void* kargs[] = {&p};
  hipLaunchCooperativeKernel((void*)fused_all, dim3(kGRID), dim3(256),
                             kargs, 0, stream);
}

// Round 12
// 325.483 us; speedup vs baseline: 2.0568x; 2.0568x over previous
//
#include <hip/hip_runtime.h>
#include <hip/hip_bf16.h>

namespace {
constexpr int kHW   = 40;
constexpr int kNPIX = kHW * kHW;        // 1600
constexpr int kDIM  = 256;
constexpr int kPADW = 42;
constexpr int kACOL = 648;              // heads * 9 * 9
constexpr float kSCALE = 0.17677669529663687f;  // 32^-0.5
constexpr int kREP = 8;                 // DIAGNOSTIC: x8 exec to expose per-kernel time
}

using bf16 = __hip_bfloat16;
typedef __attribute__((ext_vector_type(8))) short sh8;    // 8 bf16 (A/B frag)
typedef __attribute__((ext_vector_type(4))) float f32x4;  // C/D frag

static __device__ __forceinline__ bf16 f2bf(float f)  { return __float2bfloat16(f); }
static __device__ __forceinline__ float bf2f(bf16 b)  { return __bfloat162float(b); }
static __device__ __forceinline__ float sraw2f(short s) {
  union { unsigned int u; float f; } c;
  c.u = ((unsigned int)(unsigned short)s) << 16;
  return c.f;
}

// ---------------------------------------------------------------------------
// ONE fused prep kernel (segmented grid, block-uniform branches).
__global__ __launch_bounds__(256) void prep_all(
    const float* __restrict__ Wc1, const float* __restrict__ Wc2,
    const float* __restrict__ Wc3, const float* __restrict__ Wc4,
    const float* __restrict__ Wfg, const float* __restrict__ Wbg,
    const float* __restrict__ Wv,  const float* __restrict__ Wp,
    const float* __restrict__ x,   const float* __restrict__ fg,
    const float* __restrict__ bg,
    bf16* __restrict__ Wt1, bf16* __restrict__ Wt2,
    bf16* __restrict__ Wt3, bf16* __restrict__ Wt4,
    bf16* __restrict__ WaTf, bf16* __restrict__ WaTb,
    bf16* __restrict__ WvT, bf16* __restrict__ WpT,
    bf16* __restrict__ SHf, bf16* __restrict__ SHb,
    bf16* __restrict__ Pb0, bf16* __restrict__ Pb1) {
  __shared__ float smem[2304];
  int b = blockIdx.x, t = threadIdx.x;

  for (int rep = 0; rep < kREP; ++rep) {
  if (b < 1024) {                       // conv weight transform
    int w = b >> 8, oc = b & 255;
    const float* src = (w == 0) ? Wc1 : (w == 1) ? Wc2 : (w == 2) ? Wc3 : Wc4;
    bf16* dst        = (w == 0) ? Wt1 : (w == 1) ? Wt2 : (w == 2) ? Wt3 : Wt4;
    const float* s2 = src + (size_t)oc * 2304;
    for (int i = t; i < 2304; i += 256) smem[i] = s2[i];
    __syncthreads();
#pragma unroll
    for (int tap = 0; tap < 9; ++tap)
      dst[(size_t)(tap * 256 + oc) * 256 + t] = f2bf(smem[t * 9 + tap]);
  } else {
  float (*tile)[33] = (float(*)[33])smem;
  int tx = t & 31, ty = t >> 5;

  if (b < 1360) {                       // Wa transposes (256x648 -> 672x256)
    int b2 = b - 1024;
    const float* in = (b2 < 168) ? Wfg : Wbg;
    bf16* outp      = (b2 < 168) ? WaTf : WaTb;
    int rb = b2 % 168;
    int bx = rb % 21, by = rb / 21;
    int c0 = bx * 32, r0 = by * 32;
#pragma unroll
    for (int rr = ty; rr < 32; rr += 8) {
      int c = c0 + tx;
      tile[rr][tx] = (c < kACOL) ? in[(size_t)(r0 + rr) * kACOL + c] : 0.f;
    }
    __syncthreads();
#pragma unroll
    for (int rr = ty; rr < 32; rr += 8)
      outp[(size_t)(c0 + rr) * 256 + r0 + tx] = f2bf(tile[tx][rr]);
  } else if (b < 1488) {                // Wv / Wp transpose (256x256)
    int b3 = b - 1360;
    const float* in = (b3 < 64) ? Wv : Wp;
    bf16* outp      = (b3 < 64) ? WvT : WpT;
    int rb = b3 & 63;
    int bx = rb & 7, by = rb >> 3;
    int c0 = bx * 32, r0 = by * 32;
#pragma unroll
    for (int rr = ty; rr < 32; rr += 8)
      tile[rr][tx] = in[(size_t)(r0 + rr) * 256 + c0 + tx];
    __syncthreads();
#pragma unroll
    for (int rr = ty; rr < 32; rr += 8)
      outp[(size_t)(c0 + rr) * 256 + r0 + tx] = f2bf(tile[tx][rr]);
  } else if (b < 2288) {                // fg/bg CHW -> HWC bf16
    int b4 = b - 1488;
    const float* in = (b4 < 400) ? fg : bg;
    bf16* outp      = (b4 < 400) ? SHf : SHb;
    int rb = b4 % 400;
    int bx = rb % 50, by = rb / 50;
    int c0 = bx * 32, r0 = by * 32;
#pragma unroll
    for (int rr = ty; rr < 32; rr += 8)
      tile[rr][tx] = in[(size_t)(r0 + rr) * kNPIX + c0 + tx];
    __syncthreads();
#pragma unroll
    for (int rr = ty; rr < 32; rr += 8)
      outp[(size_t)(c0 + rr) * 256 + r0 + tx] = f2bf(tile[tx][rr]);
  } else if (b < 2688) {                // x CHW -> padded HWC bf16 interior
    int b5 = b - 2288;
    int bx = b5 % 50, by = b5 / 50;
    int c0 = bx * 32, r0 = by * 32;
#pragma unroll
    for (int rr = ty; rr < 32; rr += 8)
      tile[rr][tx] = x[(size_t)(r0 + rr) * kNPIX + c0 + tx];
    __syncthreads();
#pragma unroll
    for (int rr = ty; rr < 32; rr += 8) {
      int l = c0 + rr;
      int yy = l / kHW, xx = l % kHW;
      Pb0[(size_t)((yy + 1) * kPADW + xx + 1) * kDIM + r0 + tx] = f2bf(tile[tx][rr]);
    }
  } else {                              // zero pad borders of Pb0 & Pb1
    int k = b - 2688;                   // 0..163
    int py, px;
    if (k < 42)      { py = 0;          px = k; }
    else if (k < 84) { py = 41;         px = k - 42; }
    else if (k < 124){ py = k - 84 + 1; px = 0; }
    else             { py = k - 124 + 1; px = 41; }
    size_t off = (size_t)(py * kPADW + px) * kDIM + t;
    Pb0[off] = f2bf(0.f);
    Pb1[off] = f2bf(0.f);
  }
  }
  __syncthreads();
  }
}

// ---------------------------------------------------------------------------
// MFMA implicit-GEMM 3x3 conv + scale/shift + ReLU (verified R8 structure).
__global__ __launch_bounds__(256) void conv_mfma(const bf16* __restrict__ act,
                                                 const bf16* __restrict__ wt,
                                                 const float* __restrict__ sc,
                                                 const float* __restrict__ sh_,
                                                 bf16* __restrict__ outPad,
                                                 float* __restrict__ outF32) {
  int pt  = blockIdx.x;
  int oc0 = blockIdx.y * 32;
  int ty0 = (pt / 5) * 4;
  int tx0 = (pt % 5) * 8;
  int tid = threadIdx.x;
  int w = tid >> 6, lane = tid & 63, g = lane >> 4, r16 = lane & 15;

  int dy0 = r16 >> 3,       dx0 = r16 & 7;
  int dy1 = 2 + (r16 >> 3), dx1 = r16 & 7;

  __shared__ float red[4][32][33];

  for (int rep = 0; rep < kREP; ++rep) {
  f32x4 acc[2][2] = {};
  int icq = w * 64;

#pragma unroll
  for (int t = 0; t < 9; ++t) {
    int tyy = t / 3, txx = t % 3;
    const bf16* aBase0 = act + (size_t)((ty0 + dy0 + tyy) * kPADW + tx0 + dx0 + txx) * kDIM;
    const bf16* aBase1 = act + (size_t)((ty0 + dy1 + tyy) * kPADW + tx0 + dx1 + txx) * kDIM;
    const bf16* bBase  = wt + (size_t)(t * 256 + oc0 + r16) * 256;
#pragma unroll
    for (int kk = 0; kk < 2; ++kk) {
      int ic = icq + kk * 32 + g * 8;
      sh8 a0 = *(const sh8*)(aBase0 + ic);
      sh8 a1 = *(const sh8*)(aBase1 + ic);
      sh8 b0 = *(const sh8*)(bBase + ic);
      sh8 b1 = *(const sh8*)(bBase + 16 * 256 + ic);
      acc[0][0] = __builtin_amdgcn_mfma_f32_16x16x32_bf16(a0, b0, acc[0][0], 0, 0, 0);
      acc[0][1] = __builtin_amdgcn_mfma_f32_16x16x32_bf16(a0, b1, acc[0][1], 0, 0, 0);
      acc[1][0] = __builtin_amdgcn_mfma_f32_16x16x32_bf16(a1, b0, acc[1][0], 0, 0, 0);
      acc[1][1] = __builtin_amdgcn_mfma_f32_16x16x32_bf16(a1, b1, acc[1][1], 0, 0, 0);
    }
  }

#pragma unroll
  for (int mi = 0; mi < 2; ++mi)
#pragma unroll
    for (int ni = 0; ni < 2; ++ni)
#pragma unroll
      for (int q = 0; q < 4; ++q)
        red[w][mi * 16 + g * 4 + q][ni * 16 + r16] = acc[mi][ni][q];
  __syncthreads();

  int pixL = tid >> 3;
  int ocL  = (tid & 7) * 4;
  int dy = pixL >> 3, dx = pixL & 7;
  int oc = oc0 + ocL;
  int y = ty0 + dy, x = tx0 + dx;
  float v[4];
#pragma unroll
  for (int j = 0; j < 4; ++j) {
    float s = red[0][pixL][ocL + j] + red[1][pixL][ocL + j] +
              red[2][pixL][ocL + j] + red[3][pixL][ocL + j];
    v[j] = fmaxf(fmaf(s, sc[oc + j], sh_[oc + j]), 0.f);
  }
  if (outPad) {
    bf16 pk[4];
#pragma unroll
    for (int j = 0; j < 4; ++j) pk[j] = f2bf(v[j]);
    *reinterpret_cast<uint2*>(outPad + (size_t)((y + 1) * kPADW + x + 1) * kDIM + oc) =
        *reinterpret_cast<uint2*>(pk);
  } else {
#pragma unroll
    for (int j = 0; j < 4; ++j)
      outF32[(oc + j) * kNPIX + y * kHW + x] = v[j];
  }
  __syncthreads();
  }
}

// ---------------------------------------------------------------------------
// Merged triple GEMM (segmented grid, block-uniform branches).
__global__ __launch_bounds__(256) void gemm3_mfma(
    const bf16* __restrict__ Pb0, const bf16* __restrict__ WvT,
    const float* __restrict__ bv, bf16* __restrict__ Vb,
    const bf16* __restrict__ SHf, const bf16* __restrict__ WaTf,
    const float* __restrict__ bfg, bf16* __restrict__ LgF,
    const bf16* __restrict__ SHb, const bf16* __restrict__ WaTb,
    const float* __restrict__ bbg, bf16* __restrict__ LgB) {
  int b = blockIdx.x;
  const bf16 *A, *Bt;
  const float* bias;
  bf16 *oV = nullptr, *oLg = nullptr;
  bool padded = false;
  int l0, col0;
  if (b < 400) {
    padded = true; A = Pb0; Bt = WvT; bias = bv; oV = Vb;
    l0 = (b % 50) * 32; col0 = (b / 50) * 32;
  } else if (b < 1450) {
    int b2 = b - 400;
    A = SHf; Bt = WaTf; bias = bfg; oLg = LgF;
    l0 = (b2 % 50) * 32; col0 = (b2 / 50) * 32;
  } else {
    int b2 = b - 1450;
    A = SHb; Bt = WaTb; bias = bbg; oLg = LgB;
    l0 = (b2 % 50) * 32; col0 = (b2 / 50) * 32;
  }

  int tid = threadIdx.x;
  int w = tid >> 6, lane = tid & 63, g = lane >> 4, r16 = lane & 15;

  const bf16* aBase[2];
#pragma unroll
  for (int mi = 0; mi < 2; ++mi) {
    int l = l0 + mi * 16 + r16;
    if (padded) {
      int y = l / kHW, x = l % kHW;
      aBase[mi] = A + (size_t)((y + 1) * kPADW + x + 1) * kDIM;
    } else {
      aBase[mi] = A + (size_t)l * kDIM;
    }
  }
  const bf16* bBase0 = Bt + (size_t)(col0 + r16) * kDIM;
  const bf16* bBase1 = bBase0 + 16 * kDIM;

  __shared__ float red[4][32][33];

  for (int rep = 0; rep < kREP; ++rep) {
  f32x4 acc[2][2] = {};
  int icq = w * 64 + g * 8;
#pragma unroll
  for (int kk = 0; kk < 2; ++kk) {
    int ic = icq + kk * 32;
    sh8 a0 = *(const sh8*)(aBase[0] + ic);
    sh8 a1 = *(const sh8*)(aBase[1] + ic);
    sh8 b0 = *(const sh8*)(bBase0 + ic);
    sh8 b1 = *(const sh8*)(bBase1 + ic);
    acc[0][0] = __builtin_amdgcn_mfma_f32_16x16x32_bf16(a0, b0, acc[0][0], 0, 0, 0);
    acc[0][1] = __builtin_amdgcn_mfma_f32_16x16x32_bf16(a0, b1, acc[0][1], 0, 0, 0);
    acc[1][0] = __builtin_amdgcn_mfma_f32_16x16x32_bf16(a1, b0, acc[1][0], 0, 0, 0);
    acc[1][1] = __builtin_amdgcn_mfma_f32_16x16x32_bf16(a1, b1, acc[1][1], 0, 0, 0);
  }

#pragma unroll
  for (int mi = 0; mi < 2; ++mi)
#pragma unroll
    for (int ni = 0; ni < 2; ++ni)
#pragma unroll
      for (int q = 0; q < 4; ++q)
        red[w][mi * 16 + g * 4 + q][ni * 16 + r16] = acc[mi][ni][q];
  __syncthreads();

  int pixL = tid >> 3;
  int ocL  = (tid & 7) * 4;
  int l = l0 + pixL;
  int col = col0 + ocL;

  float s[4];
#pragma unroll
  for (int j = 0; j < 4; ++j)
    s[j] = red[0][pixL][ocL + j] + red[1][pixL][ocL + j] +
           red[2][pixL][ocL + j] + red[3][pixL][ocL + j];

  if (oLg) {
#pragma unroll
    for (int j = 0; j < 4; ++j)
      if (col + j < kACOL)
        oLg[(size_t)l * kACOL + col + j] = f2bf((s[j] + bias[col + j]) * kSCALE);
  } else {
    bf16 pk[4];
#pragma unroll
    for (int j = 0; j < 4; ++j) pk[j] = f2bf(s[j] + bias[col + j]);
    *reinterpret_cast<uint2*>(oV + (size_t)l * kDIM + col) =
        *reinterpret_cast<uint2*>(pk);
  }
  __syncthreads();
  }
}

// ---------------------------------------------------------------------------
// FUSED fold + projection GEMM (non-redundant, verified R8 structure).
template <int MODE>
__global__ __launch_bounds__(512) void foldproj_mfma(const bf16* __restrict__ xw,
                                                     const bf16* __restrict__ Bt,
                                                     const float* __restrict__ bias,
                                                     bf16* __restrict__ oBf) {
  __shared__ bf16 fold_s[16][264];
  int l0 = blockIdx.x * 16;
  int tid = threadIdx.x;

  for (int rep = 0; rep < kREP; ++rep) {
  {
    int s  = tid >> 5;            // 0..15 pixel in tile
    int cb = (tid & 31) * 8;      // channel base
    int l = l0 + s;
    int Y = l / kHW, X = l % kHW;
    float facc[8] = {};
#pragma unroll
    for (int i = 0; i < 3; ++i) {
      int ys = Y + 1 - i;
      if (ys < 0 || ys >= kHW) continue;
#pragma unroll
      for (int j = 0; j < 3; ++j) {
        int xs = X + 1 - j;
        if (xs < 0 || xs >= kHW) continue;
        sh8 v = *(const sh8*)(xw + (size_t)((ys * kHW + xs) * 9 + i * 3 + j) * kDIM + cb);
#pragma unroll
        for (int e = 0; e < 8; ++e) facc[e] += sraw2f(v[e]);
      }
    }
    bf16 pk[8];
#pragma unroll
    for (int e = 0; e < 8; ++e) pk[e] = f2bf(facc[e]);
    *reinterpret_cast<sh8*>(&fold_s[s][cb]) = *reinterpret_cast<sh8*>(pk);
  }
  __syncthreads();

  int w = tid >> 6, lane = tid & 63, g = lane >> 4, r16 = lane & 15;
  int col0 = w * 32;
  const bf16* bBase0 = Bt + (size_t)(col0 + r16) * kDIM;
  const bf16* bBase1 = bBase0 + 16 * kDIM;

  f32x4 acc[2] = {};
#pragma unroll
  for (int kk = 0; kk < 8; ++kk) {
    int k = kk * 32 + g * 8;
    sh8 a  = *(const sh8*)(&fold_s[r16][k]);
    sh8 b0 = *(const sh8*)(bBase0 + k);
    sh8 b1 = *(const sh8*)(bBase1 + k);
    acc[0] = __builtin_amdgcn_mfma_f32_16x16x32_bf16(a, b0, acc[0], 0, 0, 0);
    acc[1] = __builtin_amdgcn_mfma_f32_16x16x32_bf16(a, b1, acc[1], 0, 0, 0);
  }

#pragma unroll
  for (int ni = 0; ni < 2; ++ni) {
    int col = col0 + ni * 16 + r16;
    float bb = bias[col];
#pragma unroll
    for (int q = 0; q < 4; ++q) {
      int l = l0 + g * 4 + q;
      bf16 val = f2bf(acc[ni][q] + bb);
      if (MODE == 1) {
        oBf[(size_t)l * kDIM + col] = val;
      } else {
        int y = l / kHW, xx = l % kHW;
        oBf[(size_t)((y + 1) * kPADW + xx + 1) * kDIM + col] = val;
      }
    }
  }
  __syncthreads();
  }
}

// ---------------------------------------------------------------------------
// softmax over q per (head,p) + PV. Logits bf16 [l][648]; v bf16 HWC.
__global__ __launch_bounds__(256) void softmax_pv(const bf16* __restrict__ Lg,
                                                  const bf16* __restrict__ v_hwc,
                                                  bf16* __restrict__ xw) {
  __shared__ float att[kACOL];
  __shared__ float vu[9][kDIM];

  int l = blockIdx.x;
  int y = l / kHW, x = l % kHW;
  int t = threadIdx.x;

  for (int rep = 0; rep < kREP; ++rep) {
#pragma unroll
  for (int r = 0; r < 3; ++r) {
    int a = t + r * 256;
    if (a < kACOL) att[a] = bf2f(Lg[(size_t)l * kACOL + a]);
  }
#pragma unroll
  for (int q = 0; q < 9; ++q) {
    int qy = y + q / 3 - 1;
    int qx = x + q % 3 - 1;
    bool ok = (qy >= 0 && qy < kHW && qx >= 0 && qx < kHW);
    vu[q][t] = ok ? bf2f(v_hwc[(size_t)(qy * kHW + qx) * kDIM + t]) : 0.f;
  }
  __syncthreads();

  if (t < 72) {
    float* gp = &att[t * 9];
    float m = gp[0];
#pragma unroll
    for (int q = 1; q < 9; ++q) m = fmaxf(m, gp[q]);
    float e[9], sm = 0.f;
#pragma unroll
    for (int q = 0; q < 9; ++q) { e[q] = __expf(gp[q] - m); sm += e[q]; }
    float inv = 1.f / sm;
#pragma unroll
    for (int q = 0; q < 9; ++q) gp[q] = e[q] * inv;
  }
  __syncthreads();

  int n = t >> 5;
  const float* an = &att[n * 81];
#pragma unroll
  for (int p = 0; p < 9; ++p) {
    float acc = 0.f;
#pragma unroll
    for (int q = 0; q < 9; ++q)
      acc = fmaf(an[p * 9 + q], vu[q][t], acc);
    xw[(size_t)(l * 9 + p) * kDIM + t] = f2bf(acc);
  }
  __syncthreads();
  }
}

// ---------------------------------------------------------------------------
extern "C" void kernel_launch(void* const* d_in, const int* in_sizes, int n_in,
                              void* d_out, int out_size, void* d_ws, size_t ws_size,
                              hipStream_t stream) {
  const float* x   = (const float*)d_in[0];
  const float* fg  = (const float*)d_in[1];
  const float* bg  = (const float*)d_in[2];
  const float* Wc1 = (const float*)d_in[3];
  const float* s1  = (const float*)d_in[4];
  const float* b1  = (const float*)d_in[5];
  const float* Wc2 = (const float*)d_in[6];
  const float* s2  = (const float*)d_in[7];
  const float* b2  = (const float*)d_in[8];
  const float* Wv  = (const float*)d_in[9];
  const float* bv  = (const float*)d_in[10];
  const float* Wfg = (const float*)d_in[11];
  const float* bfg = (const float*)d_in[12];
  const float* Wbg = (const float*)d_in[13];
  const float* bbg = (const float*)d_in[14];
  const float* Wp  = (const float*)d_in[15];
  const float* bp  = (const float*)d_in[16];
  const float* Wc3 = (const float*)d_in[17];
  const float* s3  = (const float*)d_in[18];
  const float* b3  = (const float*)d_in[19];
  const float* Wc4 = (const float*)d_in[20];
  const float* s4  = (const float*)d_in[21];
  const float* b4  = (const float*)d_in[22];
  float* out = (float*)d_out;   // f32 NCHW

  float* ws = (float*)d_ws;
  bf16* LgF   = (bf16*)ws;                  // 1600x648 bf16  (518400 w)
  bf16* LgB   = (bf16*)(ws + 518400);       // 1600x648 bf16
  bf16* XWb   = (bf16*)(ws + 1036800);      // 3686400 bf16   (1843200 w)
  bf16* SHf   = (bf16*)(ws + 2880000);      // 409600 bf16
  bf16* SHb   = (bf16*)(ws + 3084800);
  bf16* Vb    = (bf16*)(ws + 3494400);      // v bf16 HWC
  bf16* X1b   = (bf16*)(ws + 3699200);      // x1 bf16 HWC
  bf16* Wt1   = (bf16*)(ws + 3904000);      // 4 x 589824 bf16
  bf16* Wt2   = Wt1 + 589824;
  bf16* Wt3   = Wt2 + 589824;
  bf16* Wt4   = Wt3 + 589824;
  bf16* WaTf  = (bf16*)(ws + 5083648);      // 672x256 bf16
  bf16* WaTb  = (bf16*)(ws + 5169664);
  bf16* WvT   = (bf16*)(ws + 5255680);      // 256x256 bf16
  bf16* WpT   = (bf16*)(ws + 5288448);
  bf16* Pb0   = (bf16*)(ws + 5321216);      // padded HWC bf16 (451584)
  bf16* Pb1   = (bf16*)(ws + 5547008);
  // end: 5772800 words = 23.09 MB

  // 1) fused prep (weights, transposes, padding, borders)
  prep_all<<<2852, 256, 0, stream>>>(Wc1, Wc2, Wc3, Wc4, Wfg, Wbg, Wv, Wp,
                                     x, fg, bg,
                                     Wt1, Wt2, Wt3, Wt4, WaTf, WaTb, WvT, WpT,
                                     SHf, SHb, Pb0, Pb1);

  const dim3 convGrid(50, 8);

  // 2,3) input_cbr
  conv_mfma<<<convGrid, 256, 0, stream>>>(Pb0, Wt1, s1, b1, Pb1, nullptr);
  conv_mfma<<<convGrid, 256, 0, stream>>>(Pb1, Wt2, s2, b2, Pb0, nullptr);  // h0

  // 4) merged: v = h0@Wv ; logitsF = SHf@Wfg ; logitsB = SHb@Wbg
  gemm3_mfma<<<2500, 256, 0, stream>>>(Pb0, WvT, bv, Vb,
                                       SHf, WaTf, bfg, LgF,
                                       SHb, WaTb, bbg, LgB);

  // 5,6) fg attention pass
  softmax_pv<<<kNPIX, 256, 0, stream>>>(LgF, Vb, XWb);
  foldproj_mfma<1><<<100, 512, 0, stream>>>(XWb, WpT, bp, X1b);   // x1

  // 7,8) bg attention pass (v = x1)
  softmax_pv<<<kNPIX, 256, 0, stream>>>(LgB, X1b, XWb);
  foldproj_mfma<2><<<100, 512, 0, stream>>>(XWb, WpT, bp, Pb1);   // x2 padded

  // 9,10) output_cbr
  conv_mfma<<<convGrid, 256, 0, stream>>>(Pb1, Wt3, s3, b3, Pb0, nullptr);
  conv_mfma<<<convGrid, 256, 0, stream>>>(Pb0, Wt4, s4, b4, nullptr, out);
}

// Round 13
// 128.875 us; speedup vs baseline: 5.1945x; 2.5256x over previous
//
#include <hip/hip_runtime.h>
#include <hip/hip_bf16.h>

namespace {
constexpr int kHW   = 40;
constexpr int kNPIX = kHW * kHW;        // 1600
constexpr int kDIM  = 256;
constexpr int kPADW = 42;
constexpr int kACOL = 648;              // heads * 9 * 9
constexpr float kSCALE = 0.17677669529663687f;  // 32^-0.5
}

using bf16 = __hip_bfloat16;
typedef __attribute__((ext_vector_type(8))) short sh8;    // 8 bf16 (A/B frag)
typedef __attribute__((ext_vector_type(4))) float f32x4;  // C/D frag

static __device__ __forceinline__ bf16 f2bf(float f)  { return __float2bfloat16(f); }
static __device__ __forceinline__ float bf2f(bf16 b)  { return __bfloat162float(b); }
static __device__ __forceinline__ float sraw2f(short s) {
  union { unsigned int u; float f; } c;
  c.u = ((unsigned int)(unsigned short)s) << 16;
  return c.f;
}

// ===========================================================================
// Device bodies (verified in rounds 8/11/12)
// ===========================================================================

// conv weight transform: W[oc][ic][3][3] f32 -> Wt[tap][oc][ic] bf16 (1 oc/block)
__device__ __forceinline__ void wxform_body(const float* __restrict__ src,
                                            bf16* __restrict__ dst,
                                            int oc, int t, char* smemRaw) {
  float* smem = (float*)smemRaw;
  const float* s2 = src + (size_t)oc * 2304;
  for (int i = t; i < 2304; i += 256) smem[i] = s2[i];
  __syncthreads();
#pragma unroll
  for (int tap = 0; tap < 9; ++tap)
    dst[(size_t)(tap * 256 + oc) * 256 + t] = f2bf(smem[t * 9 + tap]);
}

// tiled transpose RxC f32 -> CxR bf16 (bounds on C), one 32x32 tile/block
__device__ __forceinline__ void tpose_body(const float* __restrict__ in,
                                           bf16* __restrict__ outp,
                                           int R, int C, int Cpad,
                                           int bx, int by, int t, char* smemRaw) {
  float (*tile)[33] = (float(*)[33])smemRaw;
  int tx = t & 31, ty = t >> 5;
  int c0 = bx * 32, r0 = by * 32;
#pragma unroll
  for (int rr = ty; rr < 32; rr += 8) {
    int c = c0 + tx;
    tile[rr][tx] = (c < C) ? in[(size_t)(r0 + rr) * C + c] : 0.f;
  }
  __syncthreads();
#pragma unroll
  for (int rr = ty; rr < 32; rr += 8)
    outp[(size_t)(c0 + rr) * R + r0 + tx] = f2bf(tile[tx][rr]);
  (void)Cpad;
}

// verified R8 conv body: 32 pix x 32 oc, 4-wave K-split, LDS reduce.
__device__ __forceinline__ void conv_body(const bf16* __restrict__ act,
                                          const bf16* __restrict__ wt,
                                          const float* __restrict__ sc,
                                          const float* __restrict__ sh_,
                                          bf16* __restrict__ outPad,
                                          float* __restrict__ outF32,
                                          int vb, int tid, char* smemRaw) {
  int pt  = vb % 50;
  int oc0 = (vb / 50) * 32;
  int ty0 = (pt / 5) * 4;
  int tx0 = (pt % 5) * 8;
  int w = tid >> 6, lane = tid & 63, g = lane >> 4, r16 = lane & 15;

  int dy0 = r16 >> 3,       dx0 = r16 & 7;
  int dy1 = 2 + (r16 >> 3), dx1 = r16 & 7;

  f32x4 acc[2][2] = {};
  int icq = w * 64;

#pragma unroll
  for (int t = 0; t < 9; ++t) {
    int tyy = t / 3, txx = t % 3;
    const bf16* aBase0 = act + (size_t)((ty0 + dy0 + tyy) * kPADW + tx0 + dx0 + txx) * kDIM;
    const bf16* aBase1 = act + (size_t)((ty0 + dy1 + tyy) * kPADW + tx0 + dx1 + txx) * kDIM;
    const bf16* bBase  = wt + (size_t)(t * 256 + oc0 + r16) * 256;
#pragma unroll
    for (int kk = 0; kk < 2; ++kk) {
      int ic = icq + kk * 32 + g * 8;
      sh8 a0 = *(const sh8*)(aBase0 + ic);
      sh8 a1 = *(const sh8*)(aBase1 + ic);
      sh8 b0 = *(const sh8*)(bBase + ic);
      sh8 b1 = *(const sh8*)(bBase + 16 * 256 + ic);
      acc[0][0] = __builtin_amdgcn_mfma_f32_16x16x32_bf16(a0, b0, acc[0][0], 0, 0, 0);
      acc[0][1] = __builtin_amdgcn_mfma_f32_16x16x32_bf16(a0, b1, acc[0][1], 0, 0, 0);
      acc[1][0] = __builtin_amdgcn_mfma_f32_16x16x32_bf16(a1, b0, acc[1][0], 0, 0, 0);
      acc[1][1] = __builtin_amdgcn_mfma_f32_16x16x32_bf16(a1, b1, acc[1][1], 0, 0, 0);
    }
  }

  typedef float Red[32][33];
  Red* red = (Red*)smemRaw;
#pragma unroll
  for (int mi = 0; mi < 2; ++mi)
#pragma unroll
    for (int ni = 0; ni < 2; ++ni)
#pragma unroll
      for (int q = 0; q < 4; ++q)
        red[w][mi * 16 + g * 4 + q][ni * 16 + r16] = acc[mi][ni][q];
  __syncthreads();

  int pixL = tid >> 3;
  int ocL  = (tid & 7) * 4;
  int dy = pixL >> 3, dx = pixL & 7;
  int oc = oc0 + ocL;
  int y = ty0 + dy, x = tx0 + dx;
  float v[4];
#pragma unroll
  for (int j = 0; j < 4; ++j) {
    float s = red[0][pixL][ocL + j] + red[1][pixL][ocL + j] +
              red[2][pixL][ocL + j] + red[3][pixL][ocL + j];
    v[j] = fmaxf(fmaf(s, sc[oc + j], sh_[oc + j]), 0.f);
  }
  if (outPad) {
    bf16 pk[4];
#pragma unroll
    for (int j = 0; j < 4; ++j) pk[j] = f2bf(v[j]);
    *reinterpret_cast<uint2*>(outPad + (size_t)((y + 1) * kPADW + x + 1) * kDIM + oc) =
        *reinterpret_cast<uint2*>(pk);
  } else {
#pragma unroll
    for (int j = 0; j < 4; ++j)
      outF32[(oc + j) * kNPIX + y * kHW + x] = v[j];
  }
}

// verified gemm body (32 pix x 32 col tile, 4-wave K-split).
// mode 0: logits (bf16, scaled, bounds on col); mode 1: v (bf16 flat HWC).
__device__ __forceinline__ void gemm_body(const bf16* __restrict__ A,
                                          const bf16* __restrict__ Bt,
                                          const float* __restrict__ bias,
                                          bf16* __restrict__ oBf,
                                          bool paddedA, int mode,
                                          int l0, int col0, int tid,
                                          char* smemRaw) {
  int w = tid >> 6, lane = tid & 63, g = lane >> 4, r16 = lane & 15;

  const bf16* aBase[2];
#pragma unroll
  for (int mi = 0; mi < 2; ++mi) {
    int l = l0 + mi * 16 + r16;
    if (paddedA) {
      int y = l / kHW, x = l % kHW;
      aBase[mi] = A + (size_t)((y + 1) * kPADW + x + 1) * kDIM;
    } else {
      aBase[mi] = A + (size_t)l * kDIM;
    }
  }
  const bf16* bBase0 = Bt + (size_t)(col0 + r16) * kDIM;
  const bf16* bBase1 = bBase0 + 16 * kDIM;

  f32x4 acc[2][2] = {};
  int icq = w * 64 + g * 8;
#pragma unroll
  for (int kk = 0; kk < 2; ++kk) {
    int ic = icq + kk * 32;
    sh8 a0 = *(const sh8*)(aBase[0] + ic);
    sh8 a1 = *(const sh8*)(aBase[1] + ic);
    sh8 b0 = *(const sh8*)(bBase0 + ic);
    sh8 b1 = *(const sh8*)(bBase1 + ic);
    acc[0][0] = __builtin_amdgcn_mfma_f32_16x16x32_bf16(a0, b0, acc[0][0], 0, 0, 0);
    acc[0][1] = __builtin_amdgcn_mfma_f32_16x16x32_bf16(a0, b1, acc[0][1], 0, 0, 0);
    acc[1][0] = __builtin_amdgcn_mfma_f32_16x16x32_bf16(a1, b0, acc[1][0], 0, 0, 0);
    acc[1][1] = __builtin_amdgcn_mfma_f32_16x16x32_bf16(a1, b1, acc[1][1], 0, 0, 0);
  }

  typedef float Red[32][33];
  Red* red = (Red*)smemRaw;
#pragma unroll
  for (int mi = 0; mi < 2; ++mi)
#pragma unroll
    for (int ni = 0; ni < 2; ++ni)
#pragma unroll
      for (int q = 0; q < 4; ++q)
        red[w][mi * 16 + g * 4 + q][ni * 16 + r16] = acc[mi][ni][q];
  __syncthreads();

  int pixL = tid >> 3;
  int ocL  = (tid & 7) * 4;
  int l = l0 + pixL;
  int col = col0 + ocL;

  float s[4];
#pragma unroll
  for (int j = 0; j < 4; ++j)
    s[j] = red[0][pixL][ocL + j] + red[1][pixL][ocL + j] +
           red[2][pixL][ocL + j] + red[3][pixL][ocL + j];

  if (mode == 0) {
#pragma unroll
    for (int j = 0; j < 4; ++j)
      if (col + j < kACOL)
        oBf[(size_t)l * kACOL + col + j] = f2bf((s[j] + bias[col + j]) * kSCALE);
  } else {
    bf16 pk[4];
#pragma unroll
    for (int j = 0; j < 4; ++j) pk[j] = f2bf(s[j] + bias[col + j]);
    *reinterpret_cast<uint2*>(oBf + (size_t)l * kDIM + col) =
        *reinterpret_cast<uint2*>(pk);
  }
}

// ===========================================================================
// Dispatch kernels (segmented grids pack independent work together)
// ===========================================================================

// D1: Wt1(256) | WaTf/WaTb(336) | fg/bg->SH(800) | x->pad(400) | borders(164)
__global__ __launch_bounds__(256) void prep1(
    const float* __restrict__ Wc1,
    const float* __restrict__ Wfg, const float* __restrict__ Wbg,
    const float* __restrict__ x,   const float* __restrict__ fg,
    const float* __restrict__ bg,
    bf16* __restrict__ Wt1, bf16* __restrict__ WaTf, bf16* __restrict__ WaTb,
    bf16* __restrict__ SHf, bf16* __restrict__ SHb,
    bf16* __restrict__ Pb0, bf16* __restrict__ Pb1) {
  __shared__ __align__(16) char smemRaw[16896];
  int b = blockIdx.x, t = threadIdx.x;

  if (b < 256) { wxform_body(Wc1, Wt1, b, t, smemRaw); return; }
  if (b < 592) {
    int b2 = b - 256;
    const float* in = (b2 < 168) ? Wfg : Wbg;
    bf16* outp      = (b2 < 168) ? WaTf : WaTb;
    int rb = b2 % 168;
    tpose_body(in, outp, 256, kACOL, 672, rb % 21, rb / 21, t, smemRaw);
    return;
  }
  if (b < 1392) {                       // fg/bg CHW -> HWC bf16
    int b4 = b - 592;
    const float* in = (b4 < 400) ? fg : bg;
    bf16* outp      = (b4 < 400) ? SHf : SHb;
    int rb = b4 % 400;
    tpose_body(in, outp, 256, kNPIX, kNPIX, rb % 50, rb / 50, t, smemRaw);
    return;
  }
  if (b < 1792) {                       // x CHW -> padded HWC bf16 interior
    float (*tile)[33] = (float(*)[33])smemRaw;
    int b5 = b - 1392;
    int bx = b5 % 50, by = b5 / 50;
    int c0 = bx * 32, r0 = by * 32;
    int tx = t & 31, ty = t >> 5;
#pragma unroll
    for (int rr = ty; rr < 32; rr += 8)
      tile[rr][tx] = x[(size_t)(r0 + rr) * kNPIX + c0 + tx];
    __syncthreads();
#pragma unroll
    for (int rr = ty; rr < 32; rr += 8) {
      int l = c0 + rr;
      int yy = l / kHW, xx = l % kHW;
      Pb0[(size_t)((yy + 1) * kPADW + xx + 1) * kDIM + r0 + tx] = f2bf(tile[tx][rr]);
    }
    return;
  }
  {                                     // borders of Pb0 & Pb1
    int k = b - 1792;
    int py, px;
    if (k < 42)      { py = 0;          px = k; }
    else if (k < 84) { py = 41;         px = k - 42; }
    else if (k < 124){ py = k - 84 + 1; px = 0; }
    else             { py = k - 124 + 1; px = 41; }
    size_t off = (size_t)(py * kPADW + px) * kDIM + t;
    Pb0[off] = f2bf(0.f);
    Pb1[off] = f2bf(0.f);
  }
}

// D2: conv1(400) | logitsF(1050) | logitsB(1050) | Wt2(256) | WvT(64) | WpT(64)
__global__ __launch_bounds__(256) void stage2(
    const bf16* __restrict__ Pb0, const bf16* __restrict__ Wt1,
    const float* __restrict__ s1, const float* __restrict__ b1,
    bf16* __restrict__ Pb1,
    const bf16* __restrict__ SHf, const bf16* __restrict__ WaTf,
    const float* __restrict__ bfg, bf16* __restrict__ LgF,
    const bf16* __restrict__ SHb, const bf16* __restrict__ WaTb,
    const float* __restrict__ bbg, bf16* __restrict__ LgB,
    const float* __restrict__ Wc2, bf16* __restrict__ Wt2,
    const float* __restrict__ Wv,  bf16* __restrict__ WvT,
    const float* __restrict__ Wp,  bf16* __restrict__ WpT) {
  __shared__ __align__(16) char smemRaw[16896];
  int b = blockIdx.x, t = threadIdx.x;

  if (b < 400) { conv_body(Pb0, Wt1, s1, b1, Pb1, nullptr, b, t, smemRaw); return; }
  if (b < 1450) {
    int b2 = b - 400;
    gemm_body(SHf, WaTf, bfg, LgF, false, 0, (b2 % 50) * 32, (b2 / 50) * 32, t, smemRaw);
    return;
  }
  if (b < 2500) {
    int b2 = b - 1450;
    gemm_body(SHb, WaTb, bbg, LgB, false, 0, (b2 % 50) * 32, (b2 / 50) * 32, t, smemRaw);
    return;
  }
  if (b < 2756) { wxform_body(Wc2, Wt2, b - 2500, t, smemRaw); return; }
  if (b < 2820) {
    int rb = b - 2756;
    tpose_body(Wv, WvT, 256, 256, 256, rb & 7, rb >> 3, t, smemRaw);
    return;
  }
  {
    int rb = b - 2820;
    tpose_body(Wp, WpT, 256, 256, 256, rb & 7, rb >> 3, t, smemRaw);
  }
}

// D3: conv2(400) | Wt3(256) | Wt4(256)
__global__ __launch_bounds__(256) void stage3(
    const bf16* __restrict__ Pb1, const bf16* __restrict__ Wt2,
    const float* __restrict__ s2, const float* __restrict__ b2,
    bf16* __restrict__ Pb0,
    const float* __restrict__ Wc3, bf16* __restrict__ Wt3,
    const float* __restrict__ Wc4, bf16* __restrict__ Wt4) {
  __shared__ __align__(16) char smemRaw[16896];
  int b = blockIdx.x, t = threadIdx.x;
  if (b < 400) { conv_body(Pb1, Wt2, s2, b2, Pb0, nullptr, b, t, smemRaw); return; }
  if (b < 656) { wxform_body(Wc3, Wt3, b - 400, t, smemRaw); return; }
  wxform_body(Wc4, Wt4, b - 656, t, smemRaw);
}

// D4: v = h0(padded) @ WvT + bv (400 blocks)
__global__ __launch_bounds__(256) void vgemm(const bf16* __restrict__ Pb0,
                                             const bf16* __restrict__ WvT,
                                             const float* __restrict__ bv,
                                             bf16* __restrict__ Vb) {
  __shared__ __align__(16) char smemRaw[16896];
  int b = blockIdx.x, t = threadIdx.x;
  gemm_body(Pb0, WvT, bv, Vb, true, 1, (b % 50) * 32, (b / 50) * 32, t, smemRaw);
}

// D9/D10: standalone conv (400 blocks)
__global__ __launch_bounds__(256) void conv_k(const bf16* __restrict__ act,
                                              const bf16* __restrict__ wt,
                                              const float* __restrict__ sc,
                                              const float* __restrict__ sh_,
                                              bf16* __restrict__ outPad,
                                              float* __restrict__ outF32) {
  __shared__ __align__(16) char smemRaw[16896];
  conv_body(act, wt, sc, sh_, outPad, outF32, blockIdx.x, threadIdx.x, smemRaw);
}

// softmax over q per (head,p) + PV (verified R8).
__global__ __launch_bounds__(256) void softmax_pv(const bf16* __restrict__ Lg,
                                                  const bf16* __restrict__ v_hwc,
                                                  bf16* __restrict__ xw) {
  __shared__ float att[kACOL];
  __shared__ float vu[9][kDIM];

  int l = blockIdx.x;
  int y = l / kHW, x = l % kHW;
  int t = threadIdx.x;

#pragma unroll
  for (int r = 0; r < 3; ++r) {
    int a = t + r * 256;
    if (a < kACOL) att[a] = bf2f(Lg[(size_t)l * kACOL + a]);
  }
#pragma unroll
  for (int q = 0; q < 9; ++q) {
    int qy = y + q / 3 - 1;
    int qx = x + q % 3 - 1;
    bool ok = (qy >= 0 && qy < kHW && qx >= 0 && qx < kHW);
    vu[q][t] = ok ? bf2f(v_hwc[(size_t)(qy * kHW + qx) * kDIM + t]) : 0.f;
  }
  __syncthreads();

  if (t < 72) {
    float* gp = &att[t * 9];
    float m = gp[0];
#pragma unroll
    for (int q = 1; q < 9; ++q) m = fmaxf(m, gp[q]);
    float e[9], sm = 0.f;
#pragma unroll
    for (int q = 0; q < 9; ++q) { e[q] = __expf(gp[q] - m); sm += e[q]; }
    float inv = 1.f / sm;
#pragma unroll
    for (int q = 0; q < 9; ++q) gp[q] = e[q] * inv;
  }
  __syncthreads();

  int n = t >> 5;
  const float* an = &att[n * 81];
#pragma unroll
  for (int p = 0; p < 9; ++p) {
    float acc = 0.f;
#pragma unroll
    for (int q = 0; q < 9; ++q)
      acc = fmaf(an[p * 9 + q], vu[q][t], acc);
    xw[(size_t)(l * 9 + p) * kDIM + t] = f2bf(acc);
  }
}

// FUSED fold + projection GEMM (verified R8, 100 x 512).
template <int MODE>
__global__ __launch_bounds__(512) void foldproj_mfma(const bf16* __restrict__ xw,
                                                     const bf16* __restrict__ Bt,
                                                     const float* __restrict__ bias,
                                                     bf16* __restrict__ oBf) {
  __shared__ bf16 fold_s[16][264];
  int l0 = blockIdx.x * 16;
  int tid = threadIdx.x;

  {
    int s  = tid >> 5;
    int cb = (tid & 31) * 8;
    int l = l0 + s;
    int Y = l / kHW, X = l % kHW;
    float facc[8] = {};
#pragma unroll
    for (int i = 0; i < 3; ++i) {
      int ys = Y + 1 - i;
      if (ys < 0 || ys >= kHW) continue;
#pragma unroll
      for (int j = 0; j < 3; ++j) {
        int xs = X + 1 - j;
        if (xs < 0 || xs >= kHW) continue;
        sh8 v = *(const sh8*)(xw + (size_t)((ys * kHW + xs) * 9 + i * 3 + j) * kDIM + cb);
#pragma unroll
        for (int e = 0; e < 8; ++e) facc[e] += sraw2f(v[e]);
      }
    }
    bf16 pk[8];
#pragma unroll
    for (int e = 0; e < 8; ++e) pk[e] = f2bf(facc[e]);
    *reinterpret_cast<sh8*>(&fold_s[s][cb]) = *reinterpret_cast<sh8*>(pk);
  }
  __syncthreads();

  int w = tid >> 6, lane = tid & 63, g = lane >> 4, r16 = lane & 15;
  int col0 = w * 32;
  const bf16* bBase0 = Bt + (size_t)(col0 + r16) * kDIM;
  const bf16* bBase1 = bBase0 + 16 * kDIM;

  f32x4 acc[2] = {};
#pragma unroll
  for (int kk = 0; kk < 8; ++kk) {
    int k = kk * 32 + g * 8;
    sh8 a  = *(const sh8*)(&fold_s[r16][k]);
    sh8 b0 = *(const sh8*)(bBase0 + k);
    sh8 b1 = *(const sh8*)(bBase1 + k);
    acc[0] = __builtin_amdgcn_mfma_f32_16x16x32_bf16(a, b0, acc[0], 0, 0, 0);
    acc[1] = __builtin_amdgcn_mfma_f32_16x16x32_bf16(a, b1, acc[1], 0, 0, 0);
  }

#pragma unroll
  for (int ni = 0; ni < 2; ++ni) {
    int col = col0 + ni * 16 + r16;
    float bb = bias[col];
#pragma unroll
    for (int q = 0; q < 4; ++q) {
      int l = l0 + g * 4 + q;
      bf16 val = f2bf(acc[ni][q] + bb);
      if (MODE == 1) {
        oBf[(size_t)l * kDIM + col] = val;
      } else {
        int y = l / kHW, xx = l % kHW;
        oBf[(size_t)((y + 1) * kPADW + xx + 1) * kDIM + col] = val;
      }
    }
  }
}

// ---------------------------------------------------------------------------
extern "C" void kernel_launch(void* const* d_in, const int* in_sizes, int n_in,
                              void* d_out, int out_size, void* d_ws, size_t ws_size,
                              hipStream_t stream) {
  const float* x   = (const float*)d_in[0];
  const float* fg  = (const float*)d_in[1];
  const float* bg  = (const float*)d_in[2];
  const float* Wc1 = (const float*)d_in[3];
  const float* s1  = (const float*)d_in[4];
  const float* b1  = (const float*)d_in[5];
  const float* Wc2 = (const float*)d_in[6];
  const float* s2  = (const float*)d_in[7];
  const float* b2  = (const float*)d_in[8];
  const float* Wv  = (const float*)d_in[9];
  const float* bv  = (const float*)d_in[10];
  const float* Wfg = (const float*)d_in[11];
  const float* bfg = (const float*)d_in[12];
  const float* Wbg = (const float*)d_in[13];
  const float* bbg = (const float*)d_in[14];
  const float* Wp  = (const float*)d_in[15];
  const float* bp  = (const float*)d_in[16];
  const float* Wc3 = (const float*)d_in[17];
  const float* s3  = (const float*)d_in[18];
  const float* b3  = (const float*)d_in[19];
  const float* Wc4 = (const float*)d_in[20];
  const float* s4  = (const float*)d_in[21];
  const float* b4  = (const float*)d_in[22];
  float* out = (float*)d_out;   // f32 NCHW

  float* ws = (float*)d_ws;
  bf16* LgF   = (bf16*)ws;                  // 1600x648 bf16  (518400 w)
  bf16* LgB   = (bf16*)(ws + 518400);
  bf16* XWb   = (bf16*)(ws + 1036800);      // 3686400 bf16
  bf16* SHf   = (bf16*)(ws + 2880000);
  bf16* SHb   = (bf16*)(ws + 3084800);
  bf16* Vb    = (bf16*)(ws + 3494400);
  bf16* X1b   = (bf16*)(ws + 3699200);
  bf16* Wt1   = (bf16*)(ws + 3904000);      // 4 x 589824 bf16
  bf16* Wt2   = Wt1 + 589824;
  bf16* Wt3   = Wt2 + 589824;
  bf16* Wt4   = Wt3 + 589824;
  bf16* WaTf  = (bf16*)(ws + 5083648);
  bf16* WaTb  = (bf16*)(ws + 5169664);
  bf16* WvT   = (bf16*)(ws + 5255680);
  bf16* WpT   = (bf16*)(ws + 5288448);
  bf16* Pb0   = (bf16*)(ws + 5321216);      // padded HWC bf16 (451584)
  bf16* Pb1   = (bf16*)(ws + 5547008);
  // end: 5772800 words = 23.09 MB

  // D1: prep (first-wave requirements only)
  prep1<<<1956, 256, 0, stream>>>(Wc1, Wfg, Wbg, x, fg, bg,
                                  Wt1, WaTf, WaTb, SHf, SHb, Pb0, Pb1);

  // D2: conv1 + both logits GEMMs + Wt2/WvT/WpT transforms (2884 blocks)
  stage2<<<2884, 256, 0, stream>>>(Pb0, Wt1, s1, b1, Pb1,
                                   SHf, WaTf, bfg, LgF,
                                   SHb, WaTb, bbg, LgB,
                                   Wc2, Wt2, Wv, WvT, Wp, WpT);

  // D3: conv2 + Wt3/Wt4 transforms (912 blocks)
  stage3<<<912, 256, 0, stream>>>(Pb1, Wt2, s2, b2, Pb0, Wc3, Wt3, Wc4, Wt4);

  // D4: v = h0 @ Wv + bv
  vgemm<<<400, 256, 0, stream>>>(Pb0, WvT, bv, Vb);

  // D5,D6: fg attention pass
  softmax_pv<<<kNPIX, 256, 0, stream>>>(LgF, Vb, XWb);
  foldproj_mfma<1><<<100, 512, 0, stream>>>(XWb, WpT, bp, X1b);   // x1

  // D7,D8: bg attention pass (v = x1)
  softmax_pv<<<kNPIX, 256, 0, stream>>>(LgB, X1b, XWb);
  foldproj_mfma<2><<<100, 512, 0, stream>>>(XWb, WpT, bp, Pb1);   // x2 padded

  // D9,D10: output_cbr
  conv_k<<<400, 256, 0, stream>>>(Pb1, Wt3, s3, b3, Pb0, nullptr);
  conv_k<<<400, 256, 0, stream>>>(Pb0, Wt4, s4, b4, nullptr, out);
}

// Round 14
// 111.511 us; speedup vs baseline: 6.0034x; 1.1557x over previous
//
#include <hip/hip_runtime.h>
#include <hip/hip_bf16.h>

namespace {
constexpr int kHW   = 40;
constexpr int kNPIX = kHW * kHW;        // 1600
constexpr int kDIM  = 256;
constexpr int kPADW = 42;
constexpr int kACOL = 648;              // heads * 9 * 9
constexpr float kSCALE = 0.17677669529663687f;  // 32^-0.5
}

using bf16 = __hip_bfloat16;
typedef __attribute__((ext_vector_type(8))) short sh8;    // 8 bf16 (A/B frag)
typedef __attribute__((ext_vector_type(4))) float f32x4;  // C/D frag

static __device__ __forceinline__ bf16 f2bf(float f)  { return __float2bfloat16(f); }
static __device__ __forceinline__ float bf2f(bf16 b)  { return __bfloat162float(b); }
static __device__ __forceinline__ float sraw2f(short s) {
  union { unsigned int u; float f; } c;
  c.u = ((unsigned int)(unsigned short)s) << 16;
  return c.f;
}

// ===========================================================================
// Device bodies
// ===========================================================================

// conv weight transform: W[oc][ic][3][3] f32 -> Wt[tap][oc][ic] bf16 (1 oc/block)
__device__ __forceinline__ void wxform_body(const float* __restrict__ src,
                                            bf16* __restrict__ dst,
                                            int oc, int t, char* smemRaw) {
  float* smem = (float*)smemRaw;
  const float* s2 = src + (size_t)oc * 2304;
  for (int i = t; i < 2304; i += 256) smem[i] = s2[i];
  __syncthreads();
#pragma unroll
  for (int tap = 0; tap < 9; ++tap)
    dst[(size_t)(tap * 256 + oc) * 256 + t] = f2bf(smem[t * 9 + tap]);
}

// tiled transpose RxC f32 -> CxR bf16 (bounds on C), one 32x32 tile/block
__device__ __forceinline__ void tpose_body(const float* __restrict__ in,
                                           bf16* __restrict__ outp,
                                           int R, int C,
                                           int bx, int by, int t, char* smemRaw) {
  float (*tile)[33] = (float(*)[33])smemRaw;
  int tx = t & 31, ty = t >> 5;
  int c0 = bx * 32, r0 = by * 32;
#pragma unroll
  for (int rr = ty; rr < 32; rr += 8) {
    int c = c0 + tx;
    tile[rr][tx] = (c < C) ? in[(size_t)(r0 + rr) * C + c] : 0.f;
  }
  __syncthreads();
#pragma unroll
  for (int rr = ty; rr < 32; rr += 8)
    outp[(size_t)(c0 + rr) * R + r0 + tx] = f2bf(tile[tx][rr]);
}

// conv body v2: 32 pix x 32 oc, 4-wave K-split, A-halo staged in LDS.
// LDS: halo [60][264] bf16 (31680 B), then reused as red[4][32][33] f32.
// Numerics identical to verified R8 body (staging is a pure copy).
__device__ __forceinline__ void conv_body(const bf16* __restrict__ act,
                                          const bf16* __restrict__ wt,
                                          const float* __restrict__ sc,
                                          const float* __restrict__ sh_,
                                          bf16* __restrict__ outPad,
                                          float* __restrict__ outF32,
                                          int vb, int tid, char* smemRaw) {
  int pt  = vb % 50;
  int oc0 = (vb / 50) * 32;
  int ty0 = (pt / 5) * 4;
  int tx0 = (pt % 5) * 8;

  // ---- stage 6x10x256 A-halo (rows ty0..ty0+5, cols tx0..tx0+9, padded coords)
  bf16 (*ah)[264] = (bf16(*)[264])smemRaw;   // pixel stride 264 ch -> 2-way banks max
  for (int i = tid; i < 1920; i += 256) {    // 60 pixels x 32 ch-octs
    int pix = i >> 5;
    int ck  = (i & 31) << 3;
    int r = pix / 10, c = pix % 10;
    *(sh8*)&ah[pix][ck] =
        *(const sh8*)(act + (size_t)((ty0 + r) * kPADW + tx0 + c) * kDIM + ck);
  }
  __syncthreads();

  int w = tid >> 6, lane = tid & 63, g = lane >> 4, r16 = lane & 15;
  int dy0 = r16 >> 3,       dx0 = r16 & 7;
  int dy1 = 2 + (r16 >> 3), dx1 = r16 & 7;

  f32x4 acc[2][2] = {};
  int icq = w * 64;

#pragma unroll
  for (int t = 0; t < 9; ++t) {
    int tyy = t / 3, txx = t % 3;
    const bf16* a0p = &ah[(dy0 + tyy) * 10 + dx0 + txx][0];
    const bf16* a1p = &ah[(dy1 + tyy) * 10 + dx1 + txx][0];
    const bf16* bBase = wt + (size_t)(t * 256 + oc0 + r16) * 256;
#pragma unroll
    for (int kk = 0; kk < 2; ++kk) {
      int ic = icq + kk * 32 + g * 8;
      sh8 a0 = *(const sh8*)(a0p + ic);
      sh8 a1 = *(const sh8*)(a1p + ic);
      sh8 b0 = *(const sh8*)(bBase + ic);
      sh8 b1 = *(const sh8*)(bBase + 16 * 256 + ic);
      acc[0][0] = __builtin_amdgcn_mfma_f32_16x16x32_bf16(a0, b0, acc[0][0], 0, 0, 0);
      acc[0][1] = __builtin_amdgcn_mfma_f32_16x16x32_bf16(a0, b1, acc[0][1], 0, 0, 0);
      acc[1][0] = __builtin_amdgcn_mfma_f32_16x16x32_bf16(a1, b0, acc[1][0], 0, 0, 0);
      acc[1][1] = __builtin_amdgcn_mfma_f32_16x16x32_bf16(a1, b1, acc[1][1], 0, 0, 0);
    }
  }
  __syncthreads();                      // halo reads done; reuse LDS for red

  typedef float Red[32][33];
  Red* red = (Red*)smemRaw;
#pragma unroll
  for (int mi = 0; mi < 2; ++mi)
#pragma unroll
    for (int ni = 0; ni < 2; ++ni)
#pragma unroll
      for (int q = 0; q < 4; ++q)
        red[w][mi * 16 + g * 4 + q][ni * 16 + r16] = acc[mi][ni][q];
  __syncthreads();

  int pixL = tid >> 3;
  int ocL  = (tid & 7) * 4;
  int dy = pixL >> 3, dx = pixL & 7;
  int oc = oc0 + ocL;
  int y = ty0 + dy, x = tx0 + dx;
  float v[4];
#pragma unroll
  for (int j = 0; j < 4; ++j) {
    float s = red[0][pixL][ocL + j] + red[1][pixL][ocL + j] +
              red[2][pixL][ocL + j] + red[3][pixL][ocL + j];
    v[j] = fmaxf(fmaf(s, sc[oc + j], sh_[oc + j]), 0.f);
  }
  if (outPad) {
    bf16 pk[4];
#pragma unroll
    for (int j = 0; j < 4; ++j) pk[j] = f2bf(v[j]);
    *reinterpret_cast<uint2*>(outPad + (size_t)((y + 1) * kPADW + x + 1) * kDIM + oc) =
        *reinterpret_cast<uint2*>(pk);
  } else {
#pragma unroll
    for (int j = 0; j < 4; ++j)
      outF32[(oc + j) * kNPIX + y * kHW + x] = v[j];
  }
}

// verified gemm body (32 pix x 32 col tile, 4-wave K-split).
// mode 0: logits (bf16, scaled, bounds on col); mode 1: v (bf16 flat HWC).
__device__ __forceinline__ void gemm_body(const bf16* __restrict__ A,
                                          const bf16* __restrict__ Bt,
                                          const float* __restrict__ bias,
                                          bf16* __restrict__ oBf,
                                          bool paddedA, int mode,
                                          int l0, int col0, int tid,
                                          char* smemRaw) {
  int w = tid >> 6, lane = tid & 63, g = lane >> 4, r16 = lane & 15;

  const bf16* aBase[2];
#pragma unroll
  for (int mi = 0; mi < 2; ++mi) {
    int l = l0 + mi * 16 + r16;
    if (paddedA) {
      int y = l / kHW, x = l % kHW;
      aBase[mi] = A + (size_t)((y + 1) * kPADW + x + 1) * kDIM;
    } else {
      aBase[mi] = A + (size_t)l * kDIM;
    }
  }
  const bf16* bBase0 = Bt + (size_t)(col0 + r16) * kDIM;
  const bf16* bBase1 = bBase0 + 16 * kDIM;

  f32x4 acc[2][2] = {};
  int icq = w * 64 + g * 8;
#pragma unroll
  for (int kk = 0; kk < 2; ++kk) {
    int ic = icq + kk * 32;
    sh8 a0 = *(const sh8*)(aBase[0] + ic);
    sh8 a1 = *(const sh8*)(aBase[1] + ic);
    sh8 b0 = *(const sh8*)(bBase0 + ic);
    sh8 b1 = *(const sh8*)(bBase1 + ic);
    acc[0][0] = __builtin_amdgcn_mfma_f32_16x16x32_bf16(a0, b0, acc[0][0], 0, 0, 0);
    acc[0][1] = __builtin_amdgcn_mfma_f32_16x16x32_bf16(a0, b1, acc[0][1], 0, 0, 0);
    acc[1][0] = __builtin_amdgcn_mfma_f32_16x16x32_bf16(a1, b0, acc[1][0], 0, 0, 0);
    acc[1][1] = __builtin_amdgcn_mfma_f32_16x16x32_bf16(a1, b1, acc[1][1], 0, 0, 0);
  }

  typedef float Red[32][33];
  Red* red = (Red*)smemRaw;
#pragma unroll
  for (int mi = 0; mi < 2; ++mi)
#pragma unroll
    for (int ni = 0; ni < 2; ++ni)
#pragma unroll
      for (int q = 0; q < 4; ++q)
        red[w][mi * 16 + g * 4 + q][ni * 16 + r16] = acc[mi][ni][q];
  __syncthreads();

  int pixL = tid >> 3;
  int ocL  = (tid & 7) * 4;
  int l = l0 + pixL;
  int col = col0 + ocL;

  float s[4];
#pragma unroll
  for (int j = 0; j < 4; ++j)
    s[j] = red[0][pixL][ocL + j] + red[1][pixL][ocL + j] +
           red[2][pixL][ocL + j] + red[3][pixL][ocL + j];

  if (mode == 0) {
#pragma unroll
    for (int j = 0; j < 4; ++j)
      if (col + j < kACOL)
        oBf[(size_t)l * kACOL + col + j] = f2bf((s[j] + bias[col + j]) * kSCALE);
  } else {
    bf16 pk[4];
#pragma unroll
    for (int j = 0; j < 4; ++j) pk[j] = f2bf(s[j] + bias[col + j]);
    *reinterpret_cast<uint2*>(oBf + (size_t)l * kDIM + col) =
        *reinterpret_cast<uint2*>(pk);
  }
}

// ===========================================================================
// Dispatch kernels
// ===========================================================================

// D1: Wt1(256) | WaTf/WaTb(336) | fg/bg->SH(800) | x->pad(400) | borders(164)
__global__ __launch_bounds__(256) void prep1(
    const float* __restrict__ Wc1,
    const float* __restrict__ Wfg, const float* __restrict__ Wbg,
    const float* __restrict__ x,   const float* __restrict__ fg,
    const float* __restrict__ bg,
    bf16* __restrict__ Wt1, bf16* __restrict__ WaTf, bf16* __restrict__ WaTb,
    bf16* __restrict__ SHf, bf16* __restrict__ SHb,
    bf16* __restrict__ Pb0, bf16* __restrict__ Pb1) {
  __shared__ __align__(16) char smemRaw[16896];
  int b = blockIdx.x, t = threadIdx.x;

  if (b < 256) { wxform_body(Wc1, Wt1, b, t, smemRaw); return; }
  if (b < 592) {
    int b2 = b - 256;
    const float* in = (b2 < 168) ? Wfg : Wbg;
    bf16* outp      = (b2 < 168) ? WaTf : WaTb;
    int rb = b2 % 168;
    tpose_body(in, outp, 256, kACOL, rb % 21, rb / 21, t, smemRaw);
    return;
  }
  if (b < 1392) {
    int b4 = b - 592;
    const float* in = (b4 < 400) ? fg : bg;
    bf16* outp      = (b4 < 400) ? SHf : SHb;
    int rb = b4 % 400;
    tpose_body(in, outp, 256, kNPIX, rb % 50, rb / 50, t, smemRaw);
    return;
  }
  if (b < 1792) {                       // x CHW -> padded HWC bf16 interior
    float (*tile)[33] = (float(*)[33])smemRaw;
    int b5 = b - 1392;
    int bx = b5 % 50, by = b5 / 50;
    int c0 = bx * 32, r0 = by * 32;
    int tx = t & 31, ty = t >> 5;
#pragma unroll
    for (int rr = ty; rr < 32; rr += 8)
      tile[rr][tx] = x[(size_t)(r0 + rr) * kNPIX + c0 + tx];
    __syncthreads();
#pragma unroll
    for (int rr = ty; rr < 32; rr += 8) {
      int l = c0 + rr;
      int yy = l / kHW, xx = l % kHW;
      Pb0[(size_t)((yy + 1) * kPADW + xx + 1) * kDIM + r0 + tx] = f2bf(tile[tx][rr]);
    }
    return;
  }
  {                                     // borders of Pb0 & Pb1
    int k = b - 1792;
    int py, px;
    if (k < 42)      { py = 0;          px = k; }
    else if (k < 84) { py = 41;         px = k - 42; }
    else if (k < 124){ py = k - 84 + 1; px = 0; }
    else             { py = k - 124 + 1; px = 41; }
    size_t off = (size_t)(py * kPADW + px) * kDIM + t;
    Pb0[off] = f2bf(0.f);
    Pb1[off] = f2bf(0.f);
  }
}

// D2: conv1(400) | logitsF(1050) | logitsB(1050) | Wt2(256) | WvT(64) | WpT(64)
__global__ __launch_bounds__(256) void stage2(
    const bf16* __restrict__ Pb0, const bf16* __restrict__ Wt1,
    const float* __restrict__ s1, const float* __restrict__ b1,
    bf16* __restrict__ Pb1,
    const bf16* __restrict__ SHf, const bf16* __restrict__ WaTf,
    const float* __restrict__ bfg, bf16* __restrict__ LgF,
    const bf16* __restrict__ SHb, const bf16* __restrict__ WaTb,
    const float* __restrict__ bbg, bf16* __restrict__ LgB,
    const float* __restrict__ Wc2, bf16* __restrict__ Wt2,
    const float* __restrict__ Wv,  bf16* __restrict__ WvT,
    const float* __restrict__ Wp,  bf16* __restrict__ WpT) {
  __shared__ __align__(16) char smemRaw[31680];
  int b = blockIdx.x, t = threadIdx.x;

  if (b < 400) { conv_body(Pb0, Wt1, s1, b1, Pb1, nullptr, b, t, smemRaw); return; }
  if (b < 1450) {
    int b2 = b - 400;
    gemm_body(SHf, WaTf, bfg, LgF, false, 0, (b2 % 50) * 32, (b2 / 50) * 32, t, smemRaw);
    return;
  }
  if (b < 2500) {
    int b2 = b - 1450;
    gemm_body(SHb, WaTb, bbg, LgB, false, 0, (b2 % 50) * 32, (b2 / 50) * 32, t, smemRaw);
    return;
  }
  if (b < 2756) { wxform_body(Wc2, Wt2, b - 2500, t, smemRaw); return; }
  if (b < 2820) {
    int rb = b - 2756;
    tpose_body(Wv, WvT, 256, 256, rb & 7, rb >> 3, t, smemRaw);
    return;
  }
  {
    int rb = b - 2820;
    tpose_body(Wp, WpT, 256, 256, rb & 7, rb >> 3, t, smemRaw);
  }
}

// D3: conv2(400) | Wt3(256) | Wt4(256)
__global__ __launch_bounds__(256) void stage3(
    const bf16* __restrict__ Pb1, const bf16* __restrict__ Wt2,
    const float* __restrict__ s2, const float* __restrict__ b2,
    bf16* __restrict__ Pb0,
    const float* __restrict__ Wc3, bf16* __restrict__ Wt3,
    const float* __restrict__ Wc4, bf16* __restrict__ Wt4) {
  __shared__ __align__(16) char smemRaw[31680];
  int b = blockIdx.x, t = threadIdx.x;
  if (b < 400) { conv_body(Pb1, Wt2, s2, b2, Pb0, nullptr, b, t, smemRaw); return; }
  if (b < 656) { wxform_body(Wc3, Wt3, b - 400, t, smemRaw); return; }
  wxform_body(Wc4, Wt4, b - 656, t, smemRaw);
}

// D4: v = h0(padded) @ WvT + bv (400 blocks)
__global__ __launch_bounds__(256) void vgemm(const bf16* __restrict__ Pb0,
                                             const bf16* __restrict__ WvT,
                                             const float* __restrict__ bv,
                                             bf16* __restrict__ Vb) {
  __shared__ __align__(16) char smemRaw[16896];
  int b = blockIdx.x, t = threadIdx.x;
  gemm_body(Pb0, WvT, bv, Vb, true, 1, (b % 50) * 32, (b / 50) * 32, t, smemRaw);
}

// D9/D10: standalone conv (400 blocks)
__global__ __launch_bounds__(256) void conv_k(const bf16* __restrict__ act,
                                              const bf16* __restrict__ wt,
                                              const float* __restrict__ sc,
                                              const float* __restrict__ sh_,
                                              bf16* __restrict__ outPad,
                                              float* __restrict__ outF32) {
  __shared__ __align__(16) char smemRaw[31680];
  conv_body(act, wt, sc, sh_, outPad, outF32, blockIdx.x, threadIdx.x, smemRaw);
}

// softmax over q per (head,p) + PV (verified R8).
__global__ __launch_bounds__(256) void softmax_pv(const bf16* __restrict__ Lg,
                                                  const bf16* __restrict__ v_hwc,
                                                  bf16* __restrict__ xw) {
  __shared__ float att[kACOL];
  __shared__ float vu[9][kDIM];

  int l = blockIdx.x;
  int y = l / kHW, x = l % kHW;
  int t = threadIdx.x;

#pragma unroll
  for (int r = 0; r < 3; ++r) {
    int a = t + r * 256;
    if (a < kACOL) att[a] = bf2f(Lg[(size_t)l * kACOL + a]);
  }
#pragma unroll
  for (int q = 0; q < 9; ++q) {
    int qy = y + q / 3 - 1;
    int qx = x + q % 3 - 1;
    bool ok = (qy >= 0 && qy < kHW && qx >= 0 && qx < kHW);
    vu[q][t] = ok ? bf2f(v_hwc[(size_t)(qy * kHW + qx) * kDIM + t]) : 0.f;
  }
  __syncthreads();

  if (t < 72) {
    float* gp = &att[t * 9];
    float m = gp[0];
#pragma unroll
    for (int q = 1; q < 9; ++q) m = fmaxf(m, gp[q]);
    float e[9], sm = 0.f;
#pragma unroll
    for (int q = 0; q < 9; ++q) { e[q] = __expf(gp[q] - m); sm += e[q]; }
    float inv = 1.f / sm;
#pragma unroll
    for (int q = 0; q < 9; ++q) gp[q] = e[q] * inv;
  }
  __syncthreads();

  int n = t >> 5;
  const float* an = &att[n * 81];
#pragma unroll
  for (int p = 0; p < 9; ++p) {
    float acc = 0.f;
#pragma unroll
    for (int q = 0; q < 9; ++q)
      acc = fmaf(an[p * 9 + q], vu[q][t], acc);
    xw[(size_t)(l * 9 + p) * kDIM + t] = f2bf(acc);
  }
}

// FUSED fold + projection GEMM (verified R8, 100 x 512).
template <int MODE>
__global__ __launch_bounds__(512) void foldproj_mfma(const bf16* __restrict__ xw,
                                                     const bf16* __restrict__ Bt,
                                                     const float* __restrict__ bias,
                                                     bf16* __restrict__ oBf) {
  __shared__ bf16 fold_s[16][264];
  int l0 = blockIdx.x * 16;
  int tid = threadIdx.x;

  {
    int s  = tid >> 5;
    int cb = (tid & 31) * 8;
    int l = l0 + s;
    int Y = l / kHW, X = l % kHW;
    float facc[8] = {};
#pragma unroll
    for (int i = 0; i < 3; ++i) {
      int ys = Y + 1 - i;
      if (ys < 0 || ys >= kHW) continue;
#pragma unroll
      for (int j = 0; j < 3; ++j) {
        int xs = X + 1 - j;
        if (xs < 0 || xs >= kHW) continue;
        sh8 v = *(const sh8*)(xw + (size_t)((ys * kHW + xs) * 9 + i * 3 + j) * kDIM + cb);
#pragma unroll
        for (int e = 0; e < 8; ++e) facc[e] += sraw2f(v[e]);
      }
    }
    bf16 pk[8];
#pragma unroll
    for (int e = 0; e < 8; ++e) pk[e] = f2bf(facc[e]);
    *reinterpret_cast<sh8*>(&fold_s[s][cb]) = *reinterpret_cast<sh8*>(pk);
  }
  __syncthreads();

  int w = tid >> 6, lane = tid & 63, g = lane >> 4, r16 = lane & 15;
  int col0 = w * 32;
  const bf16* bBase0 = Bt + (size_t)(col0 + r16) * kDIM;
  const bf16* bBase1 = bBase0 + 16 * kDIM;

  f32x4 acc[2] = {};
#pragma unroll
  for (int kk = 0; kk < 8; ++kk) {
    int k = kk * 32 + g * 8;
    sh8 a  = *(const sh8*)(&fold_s[r16][k]);
    sh8 b0 = *(const sh8*)(bBase0 + k);
    sh8 b1 = *(const sh8*)(bBase1 + k);
    acc[0] = __builtin_amdgcn_mfma_f32_16x16x32_bf16(a, b0, acc[0], 0, 0, 0);
    acc[1] = __builtin_amdgcn_mfma_f32_16x16x32_bf16(a, b1, acc[1], 0, 0, 0);
  }

#pragma unroll
  for (int ni = 0; ni < 2; ++ni) {
    int col = col0 + ni * 16 + r16;
    float bb = bias[col];
#pragma unroll
    for (int q = 0; q < 4; ++q) {
      int l = l0 + g * 4 + q;
      bf16 val = f2bf(acc[ni][q] + bb);
      if (MODE == 1) {
        oBf[(size_t)l * kDIM + col] = val;
      } else {
        int y = l / kHW, xx = l % kHW;
        oBf[(size_t)((y + 1) * kPADW + xx + 1) * kDIM + col] = val;
      }
    }
  }
}

// ---------------------------------------------------------------------------
extern "C" void kernel_launch(void* const* d_in, const int* in_sizes, int n_in,
                              void* d_out, int out_size, void* d_ws, size_t ws_size,
                              hipStream_t stream) {
  const float* x   = (const float*)d_in[0];
  const float* fg  = (const float*)d_in[1];
  const float* bg  = (const float*)d_in[2];
  const float* Wc1 = (const float*)d_in[3];
  const float* s1  = (const float*)d_in[4];
  const float* b1  = (const float*)d_in[5];
  const float* Wc2 = (const float*)d_in[6];
  const float* s2  = (const float*)d_in[7];
  const float* b2  = (const float*)d_in[8];
  const float* Wv  = (const float*)d_in[9];
  const float* bv  = (const float*)d_in[10];
  const float* Wfg = (const float*)d_in[11];
  const float* bfg = (const float*)d_in[12];
  const float* Wbg = (const float*)d_in[13];
  const float* bbg = (const float*)d_in[14];
  const float* Wp  = (const float*)d_in[15];
  const float* bp  = (const float*)d_in[16];
  const float* Wc3 = (const float*)d_in[17];
  const float* s3  = (const float*)d_in[18];
  const float* b3  = (const float*)d_in[19];
  const float* Wc4 = (const float*)d_in[20];
  const float* s4  = (const float*)d_in[21];
  const float* b4  = (const float*)d_in[22];
  float* out = (float*)d_out;   // f32 NCHW

  float* ws = (float*)d_ws;
  bf16* LgF   = (bf16*)ws;                  // 1600x648 bf16  (518400 w)
  bf16* LgB   = (bf16*)(ws + 518400);
  bf16* XWb   = (bf16*)(ws + 1036800);      // 3686400 bf16
  bf16* SHf   = (bf16*)(ws + 2880000);
  bf16* SHb   = (bf16*)(ws + 3084800);
  bf16* Vb    = (bf16*)(ws + 3494400);
  bf16* X1b   = (bf16*)(ws + 3699200);
  bf16* Wt1   = (bf16*)(ws + 3904000);      // 4 x 589824 bf16
  bf16* Wt2   = Wt1 + 589824;
  bf16* Wt3   = Wt2 + 589824;
  bf16* Wt4   = Wt3 + 589824;
  bf16* WaTf  = (bf16*)(ws + 5083648);
  bf16* WaTb  = (bf16*)(ws + 5169664);
  bf16* WvT   = (bf16*)(ws + 5255680);
  bf16* WpT   = (bf16*)(ws + 5288448);
  bf16* Pb0   = (bf16*)(ws + 5321216);      // padded HWC bf16 (451584)
  bf16* Pb1   = (bf16*)(ws + 5547008);
  // end: 5772800 words = 23.09 MB

  // D1: prep (first-wave requirements only)
  prep1<<<1956, 256, 0, stream>>>(Wc1, Wfg, Wbg, x, fg, bg,
                                  Wt1, WaTf, WaTb, SHf, SHb, Pb0, Pb1);

  // D2: conv1 + both logits GEMMs + Wt2/WvT/WpT transforms (2884 blocks)
  stage2<<<2884, 256, 0, stream>>>(Pb0, Wt1, s1, b1, Pb1,
                                   SHf, WaTf, bfg, LgF,
                                   SHb, WaTb, bbg, LgB,
                                   Wc2, Wt2, Wv, WvT, Wp, WpT);

  // D3: conv2 + Wt3/Wt4 transforms (912 blocks)
  stage3<<<912, 256, 0, stream>>>(Pb1, Wt2, s2, b2, Pb0, Wc3, Wt3, Wc4, Wt4);

  // D4: v = h0 @ Wv + bv
  vgemm<<<400, 256, 0, stream>>>(Pb0, WvT, bv, Vb);

  // D5,D6: fg attention pass
  softmax_pv<<<kNPIX, 256, 0, stream>>>(LgF, Vb, XWb);
  foldproj_mfma<1><<<100, 512, 0, stream>>>(XWb, WpT, bp, X1b);   // x1

  // D7,D8: bg attention pass (v = x1)
  softmax_pv<<<kNPIX, 256, 0, stream>>>(LgB, X1b, XWb);
  foldproj_mfma<2><<<100, 512, 0, stream>>>(XWb, WpT, bp, Pb1);   // x2 padded

  // D9,D10: output_cbr
  conv_k<<<400, 256, 0, stream>>>(Pb1, Wt3, s3, b3, Pb0, nullptr);
  conv_k<<<400, 256, 0, stream>>>(Pb0, Wt4, s4, b4, nullptr, out);
}

// Round 15
// 110.465 us; speedup vs baseline: 6.0602x; 1.0095x over previous
//
#include <hip/hip_runtime.h>
#include <hip/hip_bf16.h>

namespace {
constexpr int kHW   = 40;
constexpr int kNPIX = kHW * kHW;        // 1600
constexpr int kDIM  = 256;
constexpr int kPADW = 42;
constexpr int kACOL = 648;              // heads * 9 * 9
constexpr float kSCALE = 0.17677669529663687f;  // 32^-0.5
}

using bf16 = __hip_bfloat16;
typedef __attribute__((ext_vector_type(8))) short sh8;    // 8 bf16 (A/B frag)
typedef __attribute__((ext_vector_type(4))) float f32x4;  // C/D frag

static __device__ __forceinline__ bf16 f2bf(float f)  { return __float2bfloat16(f); }
static __device__ __forceinline__ float bf2f(bf16 b)  { return __bfloat162float(b); }
static __device__ __forceinline__ float sraw2f(short s) {
  union { unsigned int u; float f; } c;
  c.u = ((unsigned int)(unsigned short)s) << 16;
  return c.f;
}

// ===========================================================================
// Device bodies
// ===========================================================================

// conv weight transform: W[oc][ic][3][3] f32 -> Wt[tap][oc][ic] bf16 (1 oc/block)
__device__ __forceinline__ void wxform_body(const float* __restrict__ src,
                                            bf16* __restrict__ dst,
                                            int oc, int t, char* smemRaw) {
  float* smem = (float*)smemRaw;
  const float* s2 = src + (size_t)oc * 2304;
  for (int i = t; i < 2304; i += 256) smem[i] = s2[i];
  __syncthreads();
#pragma unroll
  for (int tap = 0; tap < 9; ++tap)
    dst[(size_t)(tap * 256 + oc) * 256 + t] = f2bf(smem[t * 9 + tap]);
}

// tiled transpose RxC f32 -> CxR bf16 (bounds on C), one 32x32 tile/block
__device__ __forceinline__ void tpose_body(const float* __restrict__ in,
                                           bf16* __restrict__ outp,
                                           int R, int C,
                                           int bx, int by, int t, char* smemRaw) {
  float (*tile)[33] = (float(*)[33])smemRaw;
  int tx = t & 31, ty = t >> 5;
  int c0 = bx * 32, r0 = by * 32;
#pragma unroll
  for (int rr = ty; rr < 32; rr += 8) {
    int c = c0 + tx;
    tile[rr][tx] = (c < C) ? in[(size_t)(r0 + rr) * C + c] : 0.f;
  }
  __syncthreads();
#pragma unroll
  for (int rr = ty; rr < 32; rr += 8)
    outp[(size_t)(c0 + rr) * R + r0 + tx] = f2bf(tile[tx][rr]);
}

// conv body v3: 32 pix x 32 oc, 4-wave K-split, A-halo in LDS,
// tap-0 B prefetched into regs BEFORE the halo barrier (hides one L2 trip).
__device__ __forceinline__ void conv_body(const bf16* __restrict__ act,
                                          const bf16* __restrict__ wt,
                                          const float* __restrict__ sc,
                                          const float* __restrict__ sh_,
                                          bf16* __restrict__ outPad,
                                          float* __restrict__ outF32,
                                          int vb, int tid, char* smemRaw) {
  int pt  = vb % 50;
  int oc0 = (vb / 50) * 32;
  int ty0 = (pt / 5) * 4;
  int tx0 = (pt % 5) * 8;
  int w = tid >> 6, lane = tid & 63, g = lane >> 4, r16 = lane & 15;
  int icq = w * 64;

  // prefetch tap-0 B fragments (independent of halo)
  const bf16* bB0 = wt + (size_t)(oc0 + r16) * 256;
  sh8 pb0a = *(const sh8*)(bB0 + icq + g * 8);
  sh8 pb0b = *(const sh8*)(bB0 + 16 * 256 + icq + g * 8);
  sh8 pb1a = *(const sh8*)(bB0 + icq + 32 + g * 8);
  sh8 pb1b = *(const sh8*)(bB0 + 16 * 256 + icq + 32 + g * 8);

  // stage 6x10x256 A-halo
  bf16 (*ah)[264] = (bf16(*)[264])smemRaw;
  for (int i = tid; i < 1920; i += 256) {
    int pix = i >> 5;
    int ck  = (i & 31) << 3;
    int r = pix / 10, c = pix % 10;
    *(sh8*)&ah[pix][ck] =
        *(const sh8*)(act + (size_t)((ty0 + r) * kPADW + tx0 + c) * kDIM + ck);
  }
  __syncthreads();

  int dy0 = r16 >> 3,       dx0 = r16 & 7;
  int dy1 = 2 + (r16 >> 3), dx1 = r16 & 7;

  f32x4 acc[2][2] = {};

#pragma unroll
  for (int t = 0; t < 9; ++t) {
    int tyy = t / 3, txx = t % 3;
    const bf16* a0p = &ah[(dy0 + tyy) * 10 + dx0 + txx][0];
    const bf16* a1p = &ah[(dy1 + tyy) * 10 + dx1 + txx][0];
    const bf16* bBase = wt + (size_t)(t * 256 + oc0 + r16) * 256;
#pragma unroll
    for (int kk = 0; kk < 2; ++kk) {
      int ic = icq + kk * 32 + g * 8;
      sh8 a0 = *(const sh8*)(a0p + ic);
      sh8 a1 = *(const sh8*)(a1p + ic);
      sh8 b0, b1;
      if (t == 0) {
        b0 = kk ? pb1a : pb0a;
        b1 = kk ? pb1b : pb0b;
      } else {
        b0 = *(const sh8*)(bBase + ic);
        b1 = *(const sh8*)(bBase + 16 * 256 + ic);
      }
      acc[0][0] = __builtin_amdgcn_mfma_f32_16x16x32_bf16(a0, b0, acc[0][0], 0, 0, 0);
      acc[0][1] = __builtin_amdgcn_mfma_f32_16x16x32_bf16(a0, b1, acc[0][1], 0, 0, 0);
      acc[1][0] = __builtin_amdgcn_mfma_f32_16x16x32_bf16(a1, b0, acc[1][0], 0, 0, 0);
      acc[1][1] = __builtin_amdgcn_mfma_f32_16x16x32_bf16(a1, b1, acc[1][1], 0, 0, 0);
    }
  }
  __syncthreads();                      // halo reads done; reuse LDS for red

  typedef float Red[32][33];
  Red* red = (Red*)smemRaw;
#pragma unroll
  for (int mi = 0; mi < 2; ++mi)
#pragma unroll
    for (int ni = 0; ni < 2; ++ni)
#pragma unroll
      for (int q = 0; q < 4; ++q)
        red[w][mi * 16 + g * 4 + q][ni * 16 + r16] = acc[mi][ni][q];
  __syncthreads();

  int pixL = tid >> 3;
  int ocL  = (tid & 7) * 4;
  int dy = pixL >> 3, dx = pixL & 7;
  int oc = oc0 + ocL;
  int y = ty0 + dy, x = tx0 + dx;
  float v[4];
#pragma unroll
  for (int j = 0; j < 4; ++j) {
    float s = red[0][pixL][ocL + j] + red[1][pixL][ocL + j] +
              red[2][pixL][ocL + j] + red[3][pixL][ocL + j];
    v[j] = fmaxf(fmaf(s, sc[oc + j], sh_[oc + j]), 0.f);
  }
  if (outPad) {
    bf16 pk[4];
#pragma unroll
    for (int j = 0; j < 4; ++j) pk[j] = f2bf(v[j]);
    *reinterpret_cast<uint2*>(outPad + (size_t)((y + 1) * kPADW + x + 1) * kDIM + oc) =
        *reinterpret_cast<uint2*>(pk);
  } else {
#pragma unroll
    for (int j = 0; j < 4; ++j)
      outF32[(oc + j) * kNPIX + y * kHW + x] = v[j];
  }
}

// verified gemm body (32 pix x 32 col tile, 4-wave K-split).
__device__ __forceinline__ void gemm_body(const bf16* __restrict__ A,
                                          const bf16* __restrict__ Bt,
                                          const float* __restrict__ bias,
                                          bf16* __restrict__ oBf,
                                          bool paddedA, int mode,
                                          int l0, int col0, int tid,
                                          char* smemRaw) {
  int w = tid >> 6, lane = tid & 63, g = lane >> 4, r16 = lane & 15;

  const bf16* aBase[2];
#pragma unroll
  for (int mi = 0; mi < 2; ++mi) {
    int l = l0 + mi * 16 + r16;
    if (paddedA) {
      int y = l / kHW, x = l % kHW;
      aBase[mi] = A + (size_t)((y + 1) * kPADW + x + 1) * kDIM;
    } else {
      aBase[mi] = A + (size_t)l * kDIM;
    }
  }
  const bf16* bBase0 = Bt + (size_t)(col0 + r16) * kDIM;
  const bf16* bBase1 = bBase0 + 16 * kDIM;

  f32x4 acc[2][2] = {};
  int icq = w * 64 + g * 8;
#pragma unroll
  for (int kk = 0; kk < 2; ++kk) {
    int ic = icq + kk * 32;
    sh8 a0 = *(const sh8*)(aBase[0] + ic);
    sh8 a1 = *(const sh8*)(aBase[1] + ic);
    sh8 b0 = *(const sh8*)(bBase0 + ic);
    sh8 b1 = *(const sh8*)(bBase1 + ic);
    acc[0][0] = __builtin_amdgcn_mfma_f32_16x16x32_bf16(a0, b0, acc[0][0], 0, 0, 0);
    acc[0][1] = __builtin_amdgcn_mfma_f32_16x16x32_bf16(a0, b1, acc[0][1], 0, 0, 0);
    acc[1][0] = __builtin_amdgcn_mfma_f32_16x16x32_bf16(a1, b0, acc[1][0], 0, 0, 0);
    acc[1][1] = __builtin_amdgcn_mfma_f32_16x16x32_bf16(a1, b1, acc[1][1], 0, 0, 0);
  }

  typedef float Red[32][33];
  Red* red = (Red*)smemRaw;
#pragma unroll
  for (int mi = 0; mi < 2; ++mi)
#pragma unroll
    for (int ni = 0; ni < 2; ++ni)
#pragma unroll
      for (int q = 0; q < 4; ++q)
        red[w][mi * 16 + g * 4 + q][ni * 16 + r16] = acc[mi][ni][q];
  __syncthreads();

  int pixL = tid >> 3;
  int ocL  = (tid & 7) * 4;
  int l = l0 + pixL;
  int col = col0 + ocL;

  float s[4];
#pragma unroll
  for (int j = 0; j < 4; ++j)
    s[j] = red[0][pixL][ocL + j] + red[1][pixL][ocL + j] +
           red[2][pixL][ocL + j] + red[3][pixL][ocL + j];

  if (mode == 0) {
#pragma unroll
    for (int j = 0; j < 4; ++j)
      if (col + j < kACOL)
        oBf[(size_t)l * kACOL + col + j] = f2bf((s[j] + bias[col + j]) * kSCALE);
  } else {
    bf16 pk[4];
#pragma unroll
    for (int j = 0; j < 4; ++j) pk[j] = f2bf(s[j] + bias[col + j]);
    *reinterpret_cast<uint2*>(oBf + (size_t)l * kDIM + col) =
        *reinterpret_cast<uint2*>(pk);
  }
}

// ===========================================================================
// Dispatch kernels
// ===========================================================================

// D1: Wt1(256) | WaTf/WaTb(336) | fg/bg->SH(800) | x->pad(400) | borders(164)
__global__ __launch_bounds__(256) void prep1(
    const float* __restrict__ Wc1,
    const float* __restrict__ Wfg, const float* __restrict__ Wbg,
    const float* __restrict__ x,   const float* __restrict__ fg,
    const float* __restrict__ bg,
    bf16* __restrict__ Wt1, bf16* __restrict__ WaTf, bf16* __restrict__ WaTb,
    bf16* __restrict__ SHf, bf16* __restrict__ SHb,
    bf16* __restrict__ Pb0, bf16* __restrict__ Pb1) {
  __shared__ __align__(16) char smemRaw[16896];
  int b = blockIdx.x, t = threadIdx.x;

  if (b < 256) { wxform_body(Wc1, Wt1, b, t, smemRaw); return; }
  if (b < 592) {
    int b2 = b - 256;
    const float* in = (b2 < 168) ? Wfg : Wbg;
    bf16* outp      = (b2 < 168) ? WaTf : WaTb;
    int rb = b2 % 168;
    tpose_body(in, outp, 256, kACOL, rb % 21, rb / 21, t, smemRaw);
    return;
  }
  if (b < 1392) {
    int b4 = b - 592;
    const float* in = (b4 < 400) ? fg : bg;
    bf16* outp      = (b4 < 400) ? SHf : SHb;
    int rb = b4 % 400;
    tpose_body(in, outp, 256, kNPIX, rb % 50, rb / 50, t, smemRaw);
    return;
  }
  if (b < 1792) {                       // x CHW -> padded HWC bf16 interior
    float (*tile)[33] = (float(*)[33])smemRaw;
    int b5 = b - 1392;
    int bx = b5 % 50, by = b5 / 50;
    int c0 = bx * 32, r0 = by * 32;
    int tx = t & 31, ty = t >> 5;
#pragma unroll
    for (int rr = ty; rr < 32; rr += 8)
      tile[rr][tx] = x[(size_t)(r0 + rr) * kNPIX + c0 + tx];
    __syncthreads();
#pragma unroll
    for (int rr = ty; rr < 32; rr += 8) {
      int l = c0 + rr;
      int yy = l / kHW, xx = l % kHW;
      Pb0[(size_t)((yy + 1) * kPADW + xx + 1) * kDIM + r0 + tx] = f2bf(tile[tx][rr]);
    }
    return;
  }
  {                                     // borders of Pb0 & Pb1
    int k = b - 1792;
    int py, px;
    if (k < 42)      { py = 0;          px = k; }
    else if (k < 84) { py = 41;         px = k - 42; }
    else if (k < 124){ py = k - 84 + 1; px = 0; }
    else             { py = k - 124 + 1; px = 41; }
    size_t off = (size_t)(py * kPADW + px) * kDIM + t;
    Pb0[off] = f2bf(0.f);
    Pb1[off] = f2bf(0.f);
  }
}

// D2: conv1(400) | logitsF(1050) | logitsB(1050) | Wt2(256) | WvT(64) | WpT(64)
__global__ __launch_bounds__(256) void stage2(
    const bf16* __restrict__ Pb0, const bf16* __restrict__ Wt1,
    const float* __restrict__ s1, const float* __restrict__ b1,
    bf16* __restrict__ Pb1,
    const bf16* __restrict__ SHf, const bf16* __restrict__ WaTf,
    const float* __restrict__ bfg, bf16* __restrict__ LgF,
    const bf16* __restrict__ SHb, const bf16* __restrict__ WaTb,
    const float* __restrict__ bbg, bf16* __restrict__ LgB,
    const float* __restrict__ Wc2, bf16* __restrict__ Wt2,
    const float* __restrict__ Wv,  bf16* __restrict__ WvT,
    const float* __restrict__ Wp,  bf16* __restrict__ WpT) {
  __shared__ __align__(16) char smemRaw[31680];
  int b = blockIdx.x, t = threadIdx.x;

  if (b < 400) { conv_body(Pb0, Wt1, s1, b1, Pb1, nullptr, b, t, smemRaw); return; }
  if (b < 1450) {
    int b2 = b - 400;
    gemm_body(SHf, WaTf, bfg, LgF, false, 0, (b2 % 50) * 32, (b2 / 50) * 32, t, smemRaw);
    return;
  }
  if (b < 2500) {
    int b2 = b - 1450;
    gemm_body(SHb, WaTb, bbg, LgB, false, 0, (b2 % 50) * 32, (b2 / 50) * 32, t, smemRaw);
    return;
  }
  if (b < 2756) { wxform_body(Wc2, Wt2, b - 2500, t, smemRaw); return; }
  if (b < 2820) {
    int rb = b - 2756;
    tpose_body(Wv, WvT, 256, 256, rb & 7, rb >> 3, t, smemRaw);
    return;
  }
  {
    int rb = b - 2820;
    tpose_body(Wp, WpT, 256, 256, rb & 7, rb >> 3, t, smemRaw);
  }
}

// D3: conv2(400) | Wt3(256) | Wt4(256)
__global__ __launch_bounds__(256) void stage3(
    const bf16* __restrict__ Pb1, const bf16* __restrict__ Wt2,
    const float* __restrict__ s2, const float* __restrict__ b2,
    bf16* __restrict__ Pb0,
    const float* __restrict__ Wc3, bf16* __restrict__ Wt3,
    const float* __restrict__ Wc4, bf16* __restrict__ Wt4) {
  __shared__ __align__(16) char smemRaw[31680];
  int b = blockIdx.x, t = threadIdx.x;
  if (b < 400) { conv_body(Pb1, Wt2, s2, b2, Pb0, nullptr, b, t, smemRaw); return; }
  if (b < 656) { wxform_body(Wc3, Wt3, b - 400, t, smemRaw); return; }
  wxform_body(Wc4, Wt4, b - 656, t, smemRaw);
}

// D4: v = h0(padded) @ WvT + bv (400 blocks)
__global__ __launch_bounds__(256) void vgemm(const bf16* __restrict__ Pb0,
                                             const bf16* __restrict__ WvT,
                                             const float* __restrict__ bv,
                                             bf16* __restrict__ Vb) {
  __shared__ __align__(16) char smemRaw[16896];
  int b = blockIdx.x, t = threadIdx.x;
  gemm_body(Pb0, WvT, bv, Vb, true, 1, (b % 50) * 32, (b / 50) * 32, t, smemRaw);
}

// D9/D10: standalone conv (400 blocks)
__global__ __launch_bounds__(256) void conv_k(const bf16* __restrict__ act,
                                              const bf16* __restrict__ wt,
                                              const float* __restrict__ sc,
                                              const float* __restrict__ sh_,
                                              bf16* __restrict__ outPad,
                                              float* __restrict__ outF32) {
  __shared__ __align__(16) char smemRaw[31680];
  conv_body(act, wt, sc, sh_, outPad, outF32, blockIdx.x, threadIdx.x, smemRaw);
}

// softmax over q per (head,p) + PV (verified R8).
__global__ __launch_bounds__(256) void softmax_pv(const bf16* __restrict__ Lg,
                                                  const bf16* __restrict__ v_hwc,
                                                  bf16* __restrict__ xw) {
  __shared__ float att[kACOL];
  __shared__ float vu[9][kDIM];

  int l = blockIdx.x;
  int y = l / kHW, x = l % kHW;
  int t = threadIdx.x;

#pragma unroll
  for (int r = 0; r < 3; ++r) {
    int a = t + r * 256;
    if (a < kACOL) att[a] = bf2f(Lg[(size_t)l * kACOL + a]);
  }
#pragma unroll
  for (int q = 0; q < 9; ++q) {
    int qy = y + q / 3 - 1;
    int qx = x + q % 3 - 1;
    bool ok = (qy >= 0 && qy < kHW && qx >= 0 && qx < kHW);
    vu[q][t] = ok ? bf2f(v_hwc[(size_t)(qy * kHW + qx) * kDIM + t]) : 0.f;
  }
  __syncthreads();

  if (t < 72) {
    float* gp = &att[t * 9];
    float m = gp[0];
#pragma unroll
    for (int q = 1; q < 9; ++q) m = fmaxf(m, gp[q]);
    float e[9], sm = 0.f;
#pragma unroll
    for (int q = 0; q < 9; ++q) { e[q] = __expf(gp[q] - m); sm += e[q]; }
    float inv = 1.f / sm;
#pragma unroll
    for (int q = 0; q < 9; ++q) gp[q] = e[q] * inv;
  }
  __syncthreads();

  int n = t >> 5;
  const float* an = &att[n * 81];
#pragma unroll
  for (int p = 0; p < 9; ++p) {
    float acc = 0.f;
#pragma unroll
    for (int q = 0; q < 9; ++q)
      acc = fmaf(an[p * 9 + q], vu[q][t], acc);
    xw[(size_t)(l * 9 + p) * kDIM + t] = f2bf(acc);
  }
}

// FUSED fold + projection GEMM (100 x 512) with B prefetched before fold.
template <int MODE>
__global__ __launch_bounds__(512) void foldproj_mfma(const bf16* __restrict__ xw,
                                                     const bf16* __restrict__ Bt,
                                                     const float* __restrict__ bias,
                                                     bf16* __restrict__ oBf) {
  __shared__ bf16 fold_s[16][264];
  int l0 = blockIdx.x * 16;
  int tid = threadIdx.x;
  int w = tid >> 6, lane = tid & 63, g = lane >> 4, r16 = lane & 15;
  int col0 = w * 32;
  const bf16* bBase0 = Bt + (size_t)(col0 + r16) * kDIM;
  const bf16* bBase1 = bBase0 + 16 * kDIM;

  // prefetch all 16 B-octs into regs (independent of fold)
  sh8 bReg0[8], bReg1[8];
#pragma unroll
  for (int kk = 0; kk < 8; ++kk) {
    int k = kk * 32 + g * 8;
    bReg0[kk] = *(const sh8*)(bBase0 + k);
    bReg1[kk] = *(const sh8*)(bBase1 + k);
  }

  {
    int s  = tid >> 5;
    int cb = (tid & 31) * 8;
    int l = l0 + s;
    int Y = l / kHW, X = l % kHW;
    float facc[8] = {};
#pragma unroll
    for (int i = 0; i < 3; ++i) {
      int ys = Y + 1 - i;
      if (ys < 0 || ys >= kHW) continue;
#pragma unroll
      for (int j = 0; j < 3; ++j) {
        int xs = X + 1 - j;
        if (xs < 0 || xs >= kHW) continue;
        sh8 v = *(const sh8*)(xw + (size_t)((ys * kHW + xs) * 9 + i * 3 + j) * kDIM + cb);
#pragma unroll
        for (int e = 0; e < 8; ++e) facc[e] += sraw2f(v[e]);
      }
    }
    bf16 pk[8];
#pragma unroll
    for (int e = 0; e < 8; ++e) pk[e] = f2bf(facc[e]);
    *reinterpret_cast<sh8*>(&fold_s[s][cb]) = *reinterpret_cast<sh8*>(pk);
  }
  __syncthreads();

  f32x4 acc[2] = {};
#pragma unroll
  for (int kk = 0; kk < 8; ++kk) {
    int k = kk * 32 + g * 8;
    sh8 a = *(const sh8*)(&fold_s[r16][k]);
    acc[0] = __builtin_amdgcn_mfma_f32_16x16x32_bf16(a, bReg0[kk], acc[0], 0, 0, 0);
    acc[1] = __builtin_amdgcn_mfma_f32_16x16x32_bf16(a, bReg1[kk], acc[1], 0, 0, 0);
  }

#pragma unroll
  for (int ni = 0; ni < 2; ++ni) {
    int col = col0 + ni * 16 + r16;
    float bb = bias[col];
#pragma unroll
    for (int q = 0; q < 4; ++q) {
      int l = l0 + g * 4 + q;
      bf16 val = f2bf(acc[ni][q] + bb);
      if (MODE == 1) {
        oBf[(size_t)l * kDIM + col] = val;
      } else {
        int y = l / kHW, xx = l % kHW;
        oBf[(size_t)((y + 1) * kPADW + xx + 1) * kDIM + col] = val;
      }
    }
  }
}

// ---------------------------------------------------------------------------
extern "C" void kernel_launch(void* const* d_in, const int* in_sizes, int n_in,
                              void* d_out, int out_size, void* d_ws, size_t ws_size,
                              hipStream_t stream) {
  const float* x   = (const float*)d_in[0];
  const float* fg  = (const float*)d_in[1];
  const float* bg  = (const float*)d_in[2];
  const float* Wc1 = (const float*)d_in[3];
  const float* s1  = (const float*)d_in[4];
  const float* b1  = (const float*)d_in[5];
  const float* Wc2 = (const float*)d_in[6];
  const float* s2  = (const float*)d_in[7];
  const float* b2  = (const float*)d_in[8];
  const float* Wv  = (const float*)d_in[9];
  const float* bv  = (const float*)d_in[10];
  const float* Wfg = (const float*)d_in[11];
  const float* bfg = (const float*)d_in[12];
  const float* Wbg = (const float*)d_in[13];
  const float* bbg = (const float*)d_in[14];
  const float* Wp  = (const float*)d_in[15];
  const float* bp  = (const float*)d_in[16];
  const float* Wc3 = (const float*)d_in[17];
  const float* s3  = (const float*)d_in[18];
  const float* b3  = (const float*)d_in[19];
  const float* Wc4 = (const float*)d_in[20];
  const float* s4  = (const float*)d_in[21];
  const float* b4  = (const float*)d_in[22];
  float* out = (float*)d_out;   // f32 NCHW

  float* ws = (float*)d_ws;
  bf16* LgF   = (bf16*)ws;                  // 1600x648 bf16  (518400 w)
  bf16* LgB   = (bf16*)(ws + 518400);
  bf16* XWb   = (bf16*)(ws + 1036800);      // 3686400 bf16
  bf16* SHf   = (bf16*)(ws + 2880000);
  bf16* SHb   = (bf16*)(ws + 3084800);
  bf16* Vb    = (bf16*)(ws + 3494400);
  bf16* X1b   = (bf16*)(ws + 3699200);
  bf16* Wt1   = (bf16*)(ws + 3904000);      // 4 x 589824 bf16
  bf16* Wt2   = Wt1 + 589824;
  bf16* Wt3   = Wt2 + 589824;
  bf16* Wt4   = Wt3 + 589824;
  bf16* WaTf  = (bf16*)(ws + 5083648);
  bf16* WaTb  = (bf16*)(ws + 5169664);
  bf16* WvT   = (bf16*)(ws + 5255680);
  bf16* WpT   = (bf16*)(ws + 5288448);
  bf16* Pb0   = (bf16*)(ws + 5321216);      // padded HWC bf16 (451584)
  bf16* Pb1   = (bf16*)(ws + 5547008);
  // end: 5772800 words = 23.09 MB

  // D1: prep (first-wave requirements only)
  prep1<<<1956, 256, 0, stream>>>(Wc1, Wfg, Wbg, x, fg, bg,
                                  Wt1, WaTf, WaTb, SHf, SHb, Pb0, Pb1);

  // D2: conv1 + both logits GEMMs + Wt2/WvT/WpT transforms (2884 blocks)
  stage2<<<2884, 256, 0, stream>>>(Pb0, Wt1, s1, b1, Pb1,
                                   SHf, WaTf, bfg, LgF,
                                   SHb, WaTb, bbg, LgB,
                                   Wc2, Wt2, Wv, WvT, Wp, WpT);

  // D3: conv2 + Wt3/Wt4 transforms (912 blocks)
  stage3<<<912, 256, 0, stream>>>(Pb1, Wt2, s2, b2, Pb0, Wc3, Wt3, Wc4, Wt4);

  // D4: v = h0 @ Wv + bv
  vgemm<<<400, 256, 0, stream>>>(Pb0, WvT, bv, Vb);

  // D5,D6: fg attention pass
  softmax_pv<<<kNPIX, 256, 0, stream>>>(LgF, Vb, XWb);
  foldproj_mfma<1><<<100, 512, 0, stream>>>(XWb, WpT, bp, X1b);   // x1

  // D7,D8: bg attention pass (v = x1)
  softmax_pv<<<kNPIX, 256, 0, stream>>>(LgB, X1b, XWb);
  foldproj_mfma<2><<<100, 512, 0, stream>>>(XWb, WpT, bp, Pb1);   // x2 padded

  // D9,D10: output_cbr
  conv_k<<<400, 256, 0, stream>>>(Pb1, Wt3, s3, b3, Pb0, nullptr);
  conv_k<<<400, 256, 0, stream>>>(Pb0, Wt4, s4, b4, nullptr, out);
}